// Round 1
// baseline (9353.554 us; speedup 1.0000x reference)
//
#include <hip/hip_runtime.h>

// ---------------------------------------------------------------------------
// GNN forward (GraphSAGE x3 + jump + scorer) for N=100000, E=1600000, H=128.
// Key restructuring: segment_sum commutes with the linear layer, so we
// scatter raw h[src] (128 f32) per edge and do per-NODE matmuls only.
// ---------------------------------------------------------------------------

#define HDIM 128

// --- count in-degree + edge-attr aggregation (layer-invariant) -------------
__global__ __launch_bounds__(256) void edge_count_kernel(
    const int* __restrict__ dst, const float* __restrict__ ea,
    float* __restrict__ cnt, float* __restrict__ eagg, int E) {
  int e = blockIdx.x * 256 + threadIdx.x;
  if (e >= E) return;
  int d = dst[e];
  atomicAdd(&cnt[d], 1.0f);
  float2 v = *reinterpret_cast<const float2*>(&ea[2 * (size_t)e]);
  atomicAdd(&eagg[2 * (size_t)d + 0], v.x);
  atomicAdd(&eagg[2 * (size_t)d + 1], v.y);
}

// --- input projection: h0 = x @ W_in + b_in  (x is N x 4) ------------------
__global__ __launch_bounds__(256) void input_proj_kernel(
    const float* __restrict__ x, const float* __restrict__ Wi,
    const float* __restrict__ bi, float* __restrict__ h0, int N) {
  int t = blockIdx.x * 256 + threadIdx.x;
  if (t >= N * HDIM) return;
  int i = t >> 7, j = t & 127;
  const float* xr = x + (size_t)i * 4;
  float acc = bi[j];
  acc += xr[0] * Wi[0 * HDIM + j];
  acc += xr[1] * Wi[1 * HDIM + j];
  acc += xr[2] * Wi[2 * HDIM + j];
  acc += xr[3] * Wi[3 * HDIM + j];
  h0[t] = acc;
}

// --- scatter: agg[dst] += h[src]  (agg pre-initialized to h => self loop) --
__global__ __launch_bounds__(256) void scatter_kernel(
    const int* __restrict__ src, const int* __restrict__ dst,
    const float* __restrict__ h, float* __restrict__ agg, int E) {
  int t = blockIdx.x * 256 + threadIdx.x;
  int e = t >> 5;
  if (e >= E) return;
  int q = t & 31;
  int s = src[e], d = dst[e];
  float4 v = *reinterpret_cast<const float4*>(&h[(size_t)s * HDIM + q * 4]);
  float* ap = &agg[(size_t)d * HDIM + q * 4];
  atomicAdd(ap + 0, v.x);
  atomicAdd(ap + 1, v.y);
  atomicAdd(ap + 2, v.z);
  atomicAdd(ap + 3, v.w);
}

// --- fused layer GEMM: out = relu((agg/cnt)@WnA + (eagg/cnt)@WnB + h@Ws) ---
// also accumulates per-feature sum / sumsq for BatchNorm into bnstat[256].
// Block computes 32 rows x 128 cols. Thread: 4 rows x 4 cols micro-tile.
__global__ __launch_bounds__(256) void sage_gemm_kernel(
    const float* __restrict__ agg, const float* __restrict__ hprev,
    const float* __restrict__ eagg, const float* __restrict__ cnt,
    const float* __restrict__ Wn, const float* __restrict__ Ws,
    float* __restrict__ out, float* __restrict__ bnstat, int N) {
  __shared__ float sA[32][HDIM];
  __shared__ float sH[32][HDIM];
  const int t = threadIdx.x;
  const int base = blockIdx.x * 32;

  // stage rows: sA = (agg row) * 1/(cnt+1)  (pre-scale => single accumulator)
#pragma unroll
  for (int it = 0; it < 4; ++it) {
    int m = t * 4 + it * 1024;        // element in [0, 4096)
    int row = m >> 7, col = m & 127;
    int grow = base + row;
    float4 av = make_float4(0.f, 0.f, 0.f, 0.f);
    float4 hv = make_float4(0.f, 0.f, 0.f, 0.f);
    float inv = 0.f;
    if (grow < N) {
      inv = 1.0f / (cnt[grow] + 1.0f);
      av = *reinterpret_cast<const float4*>(&agg[(size_t)grow * HDIM + col]);
      hv = *reinterpret_cast<const float4*>(&hprev[(size_t)grow * HDIM + col]);
    }
    av.x *= inv; av.y *= inv; av.z *= inv; av.w *= inv;
    *reinterpret_cast<float4*>(&sA[row][col]) = av;
    *reinterpret_cast<float4*>(&sH[row][col]) = hv;
  }
  __syncthreads();

  const int c = t & 31;    // col group: cols c*4..c*4+3
  const int rg = t >> 5;   // row group: rows rg*4..rg*4+3
  float4 acc[4];
#pragma unroll
  for (int i = 0; i < 4; ++i) acc[i] = make_float4(0.f, 0.f, 0.f, 0.f);

  const float* wnp = Wn + c * 4;
  const float* wsp = Ws + c * 4;
#pragma unroll 8
  for (int k = 0; k < 128; ++k) {
    float4 wn = *reinterpret_cast<const float4*>(&wnp[(size_t)k * HDIM]);
    float4 wv = *reinterpret_cast<const float4*>(&wsp[(size_t)k * HDIM]);
#pragma unroll
    for (int i = 0; i < 4; ++i) {
      float a = sA[rg * 4 + i][k];
      float hh = sH[rg * 4 + i][k];
      acc[i].x += a * wn.x + hh * wv.x;
      acc[i].y += a * wn.y + hh * wv.y;
      acc[i].z += a * wn.z + hh * wv.z;
      acc[i].w += a * wn.w + hh * wv.w;
    }
  }

  // epilogue: edge-attr rows of Wn (rows 128,129), relu, store, BN partials
  float4 we0 = *reinterpret_cast<const float4*>(&Wn[(size_t)128 * HDIM + c * 4]);
  float4 we1 = *reinterpret_cast<const float4*>(&Wn[(size_t)129 * HDIM + c * 4]);
  float4 ps = make_float4(0.f, 0.f, 0.f, 0.f);
  float4 pq = make_float4(0.f, 0.f, 0.f, 0.f);
#pragma unroll
  for (int i = 0; i < 4; ++i) {
    int row = base + rg * 4 + i;
    if (row < N) {
      float inv = 1.0f / (cnt[row] + 1.0f);
      float e0 = eagg[2 * (size_t)row + 0] * inv;
      float e1 = eagg[2 * (size_t)row + 1] * inv;
      float4 v;
      v.x = fmaxf(acc[i].x + e0 * we0.x + e1 * we1.x, 0.f);
      v.y = fmaxf(acc[i].y + e0 * we0.y + e1 * we1.y, 0.f);
      v.z = fmaxf(acc[i].z + e0 * we0.z + e1 * we1.z, 0.f);
      v.w = fmaxf(acc[i].w + e0 * we0.w + e1 * we1.w, 0.f);
      *reinterpret_cast<float4*>(&out[(size_t)row * HDIM + c * 4]) = v;
      ps.x += v.x; ps.y += v.y; ps.z += v.z; ps.w += v.w;
      pq.x += v.x * v.x; pq.y += v.y * v.y; pq.z += v.z * v.z; pq.w += v.w * v.w;
    }
  }

  // block-level BN partial reduction (reuse LDS), then 2 atomics per column
  __syncthreads();
  float* sp = &sA[0][0];
  float* sq = &sH[0][0];
  *reinterpret_cast<float4*>(&sp[rg * 128 + c * 4]) = ps;
  *reinterpret_cast<float4*>(&sq[rg * 128 + c * 4]) = pq;
  __syncthreads();
  if (t < 128) {
    float s = 0.f, s2 = 0.f;
#pragma unroll
    for (int rr = 0; rr < 8; ++rr) {
      s += sp[rr * 128 + t];
      s2 += sq[rr * 128 + t];
    }
    atomicAdd(&bnstat[t], s);
    atomicAdd(&bnstat[128 + t], s2);
  }
}

// --- BN finalize: A = gamma*rsqrt(var+eps), B = beta - mean*A --------------
__global__ void bn_finalize_kernel(const float* __restrict__ stat,
                                   const float* __restrict__ gamma,
                                   const float* __restrict__ beta,
                                   float* __restrict__ ab, float invN) {
  int j = threadIdx.x;  // 128 threads
  float mean = stat[j] * invN;
  float var = stat[128 + j] * invN - mean * mean;
  float inv = 1.0f / sqrtf(var + 1e-5f);
  float A = inv * gamma[j];
  ab[j] = A;
  ab[128 + j] = beta[j] - mean * A;
}

// --- apply BN + per-node L2 normalize (in place). 1 wave per node. ---------
__global__ __launch_bounds__(64) void bn_l2_kernel(float* __restrict__ h,
                                                   const float* __restrict__ ab,
                                                   int N) {
  int i = blockIdx.x;
  if (i >= N) return;
  int lane = threadIdx.x;  // 0..63, handles cols lane*2, lane*2+1
  size_t off = (size_t)i * HDIM + lane * 2;
  float2 v = *reinterpret_cast<const float2*>(&h[off]);
  float A0 = ab[lane * 2 + 0], A1 = ab[lane * 2 + 1];
  float B0 = ab[128 + lane * 2 + 0], B1 = ab[128 + lane * 2 + 1];
  float y0 = v.x * A0 + B0;
  float y1 = v.y * A1 + B1;
  float s = y0 * y0 + y1 * y1;
#pragma unroll
  for (int m = 32; m > 0; m >>= 1) s += __shfl_xor(s, m, 64);
  float nrm = fmaxf(sqrtf(s), 1e-12f);
  float inv = 1.0f / nrm;
  float2 o;
  o.x = y0 * inv;
  o.y = y1 * inv;
  *reinterpret_cast<float2*>(&h[off]) = o;
}

// --- jump concat @ W_jump + relu, then scorer MLP --------------------------
// Block: 32 rows. Stage concat(h1,h2,h3) rows (32x384) in LDS.
__global__ __launch_bounds__(256) void jump_score_kernel(
    const float* __restrict__ h1, const float* __restrict__ h2,
    const float* __restrict__ h3, const float* __restrict__ Wj,
    const float* __restrict__ bj, const float* __restrict__ W1p,
    const float* __restrict__ b1p, const float* __restrict__ W2p,
    const float* __restrict__ b2p, float* __restrict__ outp, int N) {
  __shared__ float smem[32 * 384];  // 48 KB, reused in 3 phases
  const int t = threadIdx.x;
  const int base = blockIdx.x * 32;

  // stage concat rows: 3072 float4 by 256 threads
#pragma unroll
  for (int it = 0; it < 12; ++it) {
    int f = t + it * 256;       // float4 index
    int row = f / 96;           // 96 float4 per 384-row
    int col = (f % 96) * 4;
    int grow = base + row;
    float4 v = make_float4(0.f, 0.f, 0.f, 0.f);
    if (grow < N) {
      const float* srcp = (col < 128)
                              ? &h1[(size_t)grow * HDIM + col]
                              : (col < 256) ? &h2[(size_t)grow * HDIM + col - 128]
                                            : &h3[(size_t)grow * HDIM + col - 256];
      v = *reinterpret_cast<const float4*>(srcp);
    }
    *reinterpret_cast<float4*>(&smem[row * 384 + col]) = v;
  }
  __syncthreads();

  const int c = t & 31, rg = t >> 5;
  float4 acc[4];
#pragma unroll
  for (int i = 0; i < 4; ++i) acc[i] = make_float4(0.f, 0.f, 0.f, 0.f);
  const float* wp = Wj + c * 4;
#pragma unroll 8
  for (int k = 0; k < 384; ++k) {
    float4 w = *reinterpret_cast<const float4*>(&wp[(size_t)k * HDIM]);
#pragma unroll
    for (int i = 0; i < 4; ++i) {
      float a = smem[(rg * 4 + i) * 384 + k];
      acc[i].x += a * w.x;
      acc[i].y += a * w.y;
      acc[i].z += a * w.z;
      acc[i].w += a * w.w;
    }
  }
  float4 bb = *reinterpret_cast<const float4*>(&bj[c * 4]);
  __syncthreads();  // smem (concat) now dead; reuse as g [32][128]
  float* sG = smem;
#pragma unroll
  for (int i = 0; i < 4; ++i) {
    float4 g;
    g.x = fmaxf(acc[i].x + bb.x, 0.f);
    g.y = fmaxf(acc[i].y + bb.y, 0.f);
    g.z = fmaxf(acc[i].z + bb.z, 0.f);
    g.w = fmaxf(acc[i].w + bb.w, 0.f);
    *reinterpret_cast<float4*>(&sG[(rg * 4 + i) * 128 + c * 4]) = g;
  }
  __syncthreads();

  // scorer layer 1: s1[row][m] = relu(b1[m] + g[row] . W1[:,m]), m<64
  float* sS = smem + 32 * 128;  // [32][64]
  const int m = t & 63, g4 = t >> 6;  // 4 groups x 8 rows
  float a2[8];
#pragma unroll
  for (int i = 0; i < 8; ++i) a2[i] = b1p[m];
#pragma unroll 4
  for (int k = 0; k < 128; ++k) {
    float w = W1p[(size_t)k * 64 + m];
#pragma unroll
    for (int i = 0; i < 8; ++i) a2[i] += sG[(g4 * 8 + i) * 128 + k] * w;
  }
#pragma unroll
  for (int i = 0; i < 8; ++i) sS[(g4 * 8 + i) * 64 + m] = fmaxf(a2[i], 0.f);
  __syncthreads();

  // scorer layer 2: score = b2 + s1 . W2
  if (t < 32) {
    int row = base + t;
    if (row < N) {
      float s = b2p[0];
#pragma unroll 8
      for (int mm = 0; mm < 64; ++mm) s += sS[t * 64 + mm] * W2p[mm];
      outp[row] = s;
    }
  }
}

// ---------------------------------------------------------------------------
extern "C" void kernel_launch(void* const* d_in, const int* in_sizes, int n_in,
                              void* d_out, int out_size, void* d_ws, size_t ws_size,
                              hipStream_t stream) {
  const float* x      = (const float*)d_in[0];
  const int*   ei     = (const int*)d_in[1];
  const float* eattr  = (const float*)d_in[2];
  const float* W_in   = (const float*)d_in[3];
  const float* b_in   = (const float*)d_in[4];
  const float* W_jump = (const float*)d_in[5];
  const float* b_jump = (const float*)d_in[6];
  const float* W1     = (const float*)d_in[7];
  const float* b1     = (const float*)d_in[8];
  const float* W2     = (const float*)d_in[9];
  const float* b2     = (const float*)d_in[10];
  const float* Wn[3] = {(const float*)d_in[11], (const float*)d_in[15], (const float*)d_in[19]};
  const float* Ws[3] = {(const float*)d_in[12], (const float*)d_in[16], (const float*)d_in[20]};
  const float* gm[3] = {(const float*)d_in[13], (const float*)d_in[17], (const float*)d_in[21]};
  const float* bt[3] = {(const float*)d_in[14], (const float*)d_in[18], (const float*)d_in[22]};

  const int N = in_sizes[0] / 4;
  const int E = in_sizes[2] / 2;
  const int* srcp = ei;
  const int* dstp = ei + (size_t)E;

  float* ws = (float*)d_ws;
  const size_t nh = (size_t)N * HDIM;
  float* h0     = ws;
  float* h1     = h0 + nh;
  float* h2     = h1 + nh;
  float* h3     = h2 + nh;
  float* agg    = h3 + nh;
  float* cnt    = agg + nh;          // N
  float* eagg   = cnt + N;           // 2N
  float* bnstat = eagg + 2 * (size_t)N;  // 256
  float* bnab   = bnstat + 256;          // 256

  float* hbuf[4] = {h0, h1, h2, h3};

  // layer-invariant: cnt, eagg
  hipMemsetAsync(cnt, 0, (size_t)(3 * (size_t)N) * sizeof(float), stream);
  edge_count_kernel<<<(E + 255) / 256, 256, 0, stream>>>(dstp, eattr, cnt, eagg, E);

  // input projection
  input_proj_kernel<<<((size_t)N * HDIM + 255) / 256, 256, 0, stream>>>(x, W_in, b_in, h0, N);

  for (int l = 0; l < 3; ++l) {
    hipMemcpyAsync(agg, hbuf[l], nh * sizeof(float), hipMemcpyDeviceToDevice, stream);
    hipMemsetAsync(bnstat, 0, 256 * sizeof(float), stream);
    scatter_kernel<<<((size_t)E * 32 + 255) / 256, 256, 0, stream>>>(srcp, dstp, hbuf[l], agg, E);
    sage_gemm_kernel<<<(N + 31) / 32, 256, 0, stream>>>(agg, hbuf[l], eagg, cnt,
                                                        Wn[l], Ws[l], hbuf[l + 1], bnstat, N);
    bn_finalize_kernel<<<1, 128, 0, stream>>>(bnstat, gm[l], bt[l], bnab, 1.0f / (float)N);
    bn_l2_kernel<<<N, 64, 0, stream>>>(hbuf[l + 1], bnab, N);
  }

  jump_score_kernel<<<(N + 31) / 32, 256, 0, stream>>>(h1, h2, h3, W_jump, b_jump,
                                                       W1, b1, W2, b2, (float*)d_out, N);
}

// Round 2
// 1489.829 us; speedup vs baseline: 6.2783x; 6.2783x over previous
//
#include <hip/hip_runtime.h>

// ---------------------------------------------------------------------------
// GNN forward (GraphSAGE x3 + jump + scorer), N=100000, E=1600000, H=128.
// Round 2: CSR-by-dst + gather-side aggregation (no float atomics on agg),
// layer-0 aggregation done in x-space (4 wide), jump kernel re-tiled (24KB LDS).
// ---------------------------------------------------------------------------

#define HDIM 128

// --- per-edge count + edge-attr aggregation (layer-invariant) --------------
__global__ __launch_bounds__(256) void count_kernel(
    const int* __restrict__ dst, const float* __restrict__ ea,
    int* __restrict__ cnt, float* __restrict__ eagg, int E) {
  int e = blockIdx.x * 256 + threadIdx.x;
  if (e >= E) return;
  int d = dst[e];
  atomicAdd(&cnt[d], 1);
  float2 v = *reinterpret_cast<const float2*>(&ea[2 * (size_t)e]);
  atomicAdd(&eagg[2 * (size_t)d + 0], v.x);
  atomicAdd(&eagg[2 * (size_t)d + 1], v.y);
}

// --- scan stage A: per-128-chunk sums --------------------------------------
__global__ __launch_bounds__(128) void scan_block_sum(
    const int* __restrict__ cnt, int* __restrict__ bsum, int N) {
  __shared__ int sd[128];
  int t = threadIdx.x;
  int i = blockIdx.x * 128 + t;
  sd[t] = (i < N) ? cnt[i] : 0;
  __syncthreads();
  for (int off = 64; off > 0; off >>= 1) {
    if (t < off) sd[t] += sd[t + off];
    __syncthreads();
  }
  if (t == 0) bsum[blockIdx.x] = sd[0];
}

// --- scan stage B: exclusive scan of chunk sums (nch <= 1024) --------------
__global__ __launch_bounds__(256) void scan_partials(
    const int* __restrict__ bsum, int* __restrict__ boff, int nch) {
  __shared__ int sd[256];
  int t = threadIdx.x;
  int base = t * 4;
  int v0 = (base + 0 < nch) ? bsum[base + 0] : 0;
  int v1 = (base + 1 < nch) ? bsum[base + 1] : 0;
  int v2 = (base + 2 < nch) ? bsum[base + 2] : 0;
  int v3 = (base + 3 < nch) ? bsum[base + 3] : 0;
  sd[t] = v0 + v1 + v2 + v3;
  __syncthreads();
  for (int off = 1; off < 256; off <<= 1) {
    int x = sd[t];
    int y = (t >= off) ? sd[t - off] : 0;
    __syncthreads();
    sd[t] = x + y;
    __syncthreads();
  }
  int run = (t == 0) ? 0 : sd[t - 1];
  if (base + 0 < nch) boff[base + 0] = run; run += v0;
  if (base + 1 < nch) boff[base + 1] = run; run += v1;
  if (base + 2 < nch) boff[base + 2] = run; run += v2;
  if (base + 3 < nch) boff[base + 3] = run;
}

// --- scan stage C: per-element exclusive offsets -> rowstart, rowcur -------
__global__ __launch_bounds__(128) void scan_final(
    const int* __restrict__ cnt, const int* __restrict__ boff,
    int* __restrict__ rs, int* __restrict__ rc, int N) {
  __shared__ int sd[128];
  int t = threadIdx.x, b = blockIdx.x;
  int i = b * 128 + t;
  int v = (i < N) ? cnt[i] : 0;
  sd[t] = v;
  __syncthreads();
  for (int off = 1; off < 128; off <<= 1) {
    int x = sd[t];
    int y = (t >= off) ? sd[t - off] : 0;
    __syncthreads();
    sd[t] = x + y;
    __syncthreads();
  }
  int excl = boff[b] + ((t == 0) ? 0 : sd[t - 1]);
  if (i < N) { rs[i] = excl; rc[i] = excl; }
}

// --- CSR fill: cidx grouped by dst (order within a row irrelevant) ---------
__global__ __launch_bounds__(256) void fill_kernel(
    const int* __restrict__ src, const int* __restrict__ dst,
    int* __restrict__ rc, int* __restrict__ cidx, int E) {
  int e = blockIdx.x * 256 + threadIdx.x;
  if (e >= E) return;
  int d = dst[e];
  int pos = atomicAdd(&rc[d], 1);
  cidx[pos] = src[e];
}

// --- layer-0 aggregation in x-space (4 floats/node, incl self) -------------
__global__ __launch_bounds__(256) void aggx_kernel(
    const float* __restrict__ x, const int* __restrict__ rs,
    const int* __restrict__ re, const int* __restrict__ cidx,
    float* __restrict__ aggx, int N) {
  int i = blockIdx.x * 256 + threadIdx.x;
  if (i >= N) return;
  float4 a = *reinterpret_cast<const float4*>(&x[(size_t)i * 4]);
  float4 b = make_float4(0.f, 0.f, 0.f, 0.f);
  int p = rs[i], e = re[i];
  for (; p + 1 < e; p += 2) {
    int s0 = cidx[p], s1 = cidx[p + 1];
    float4 v0 = *reinterpret_cast<const float4*>(&x[(size_t)s0 * 4]);
    float4 v1 = *reinterpret_cast<const float4*>(&x[(size_t)s1 * 4]);
    a.x += v0.x; a.y += v0.y; a.z += v0.z; a.w += v0.w;
    b.x += v1.x; b.y += v1.y; b.z += v1.z; b.w += v1.w;
  }
  if (p < e) {
    int s = cidx[p];
    float4 v = *reinterpret_cast<const float4*>(&x[(size_t)s * 4]);
    a.x += v.x; a.y += v.y; a.z += v.z; a.w += v.w;
  }
  a.x += b.x; a.y += b.y; a.z += b.z; a.w += b.w;
  *reinterpret_cast<float4*>(&aggx[(size_t)i * 4]) = a;
}

// --- layers 1,2 aggregation: one wave per node, float2 per lane ------------
__global__ __launch_bounds__(256) void csr_agg_kernel(
    const float* __restrict__ h, const int* __restrict__ rs,
    const int* __restrict__ re, const int* __restrict__ cidx,
    float* __restrict__ agg, int N) {
  int i = blockIdx.x * 4 + (threadIdx.x >> 6);
  if (i >= N) return;
  int lane = threadIdx.x & 63;
  const float* hb = h + (size_t)lane * 2;
  float2 a0 = *reinterpret_cast<const float2*>(&hb[(size_t)i * HDIM]);  // self
  float2 a1 = make_float2(0.f, 0.f), a2 = make_float2(0.f, 0.f), a3 = make_float2(0.f, 0.f);
  int p = rs[i], e = re[i];
  for (; p + 3 < e; p += 4) {
    int s0 = cidx[p], s1 = cidx[p + 1], s2 = cidx[p + 2], s3 = cidx[p + 3];
    float2 v0 = *reinterpret_cast<const float2*>(&hb[(size_t)s0 * HDIM]);
    float2 v1 = *reinterpret_cast<const float2*>(&hb[(size_t)s1 * HDIM]);
    float2 v2 = *reinterpret_cast<const float2*>(&hb[(size_t)s2 * HDIM]);
    float2 v3 = *reinterpret_cast<const float2*>(&hb[(size_t)s3 * HDIM]);
    a0.x += v0.x; a0.y += v0.y;
    a1.x += v1.x; a1.y += v1.y;
    a2.x += v2.x; a2.y += v2.y;
    a3.x += v3.x; a3.y += v3.y;
  }
  for (; p < e; ++p) {
    int s = cidx[p];
    float2 v = *reinterpret_cast<const float2*>(&hb[(size_t)s * HDIM]);
    a0.x += v.x; a0.y += v.y;
  }
  a0.x += a1.x + a2.x + a3.x;
  a0.y += a1.y + a2.y + a3.y;
  *reinterpret_cast<float2*>(&agg[(size_t)i * HDIM + lane * 2]) = a0;
}

// --- fused layer GEMM ------------------------------------------------------
// L0=false: sA = agg*inv, sH = hprev (A0=agg, A1=hprev)
// L0=true : sA = (aggx@Wi)*inv + bi, sH = x@Wi + bi (A0=aggx[N,4], A1=x[N,4])
// out = relu(sA@Wn[0:128] + (eagg*inv)@Wn[128:130] + sH@Ws); BN partials.
template <bool L0>
__global__ __launch_bounds__(256) void sage_gemm_kernel(
    const float* __restrict__ A0, const float* __restrict__ A1,
    const float* __restrict__ Wi, const float* __restrict__ bi,
    const float* __restrict__ eagg, const int* __restrict__ cnt,
    const float* __restrict__ Wn, const float* __restrict__ Ws,
    float* __restrict__ out, float* __restrict__ bnstat, int N) {
  __shared__ float sA[32][HDIM];
  __shared__ float sH[32][HDIM];
  const int t = threadIdx.x;
  const int base = blockIdx.x * 32;

#pragma unroll
  for (int it = 0; it < 4; ++it) {
    int m = t * 4 + it * 1024;
    int row = m >> 7, col = m & 127;
    int grow = base + row;
    float4 av = make_float4(0.f, 0.f, 0.f, 0.f);
    float4 hv = make_float4(0.f, 0.f, 0.f, 0.f);
    if (grow < N) {
      float inv = 1.0f / ((float)cnt[grow] + 1.0f);
      if (L0) {
        float4 ax = *reinterpret_cast<const float4*>(&A0[(size_t)grow * 4]);
        float4 xr = *reinterpret_cast<const float4*>(&A1[(size_t)grow * 4]);
        float4 w0 = *reinterpret_cast<const float4*>(&Wi[0 * HDIM + col]);
        float4 w1 = *reinterpret_cast<const float4*>(&Wi[1 * HDIM + col]);
        float4 w2 = *reinterpret_cast<const float4*>(&Wi[2 * HDIM + col]);
        float4 w3 = *reinterpret_cast<const float4*>(&Wi[3 * HDIM + col]);
        float4 b4 = *reinterpret_cast<const float4*>(&bi[col]);
        av.x = b4.x + inv * (ax.x * w0.x + ax.y * w1.x + ax.z * w2.x + ax.w * w3.x);
        av.y = b4.y + inv * (ax.x * w0.y + ax.y * w1.y + ax.z * w2.y + ax.w * w3.y);
        av.z = b4.z + inv * (ax.x * w0.z + ax.y * w1.z + ax.z * w2.z + ax.w * w3.z);
        av.w = b4.w + inv * (ax.x * w0.w + ax.y * w1.w + ax.z * w2.w + ax.w * w3.w);
        hv.x = b4.x + (xr.x * w0.x + xr.y * w1.x + xr.z * w2.x + xr.w * w3.x);
        hv.y = b4.y + (xr.x * w0.y + xr.y * w1.y + xr.z * w2.y + xr.w * w3.y);
        hv.z = b4.z + (xr.x * w0.z + xr.y * w1.z + xr.z * w2.z + xr.w * w3.z);
        hv.w = b4.w + (xr.x * w0.w + xr.y * w1.w + xr.z * w2.w + xr.w * w3.w);
      } else {
        av = *reinterpret_cast<const float4*>(&A0[(size_t)grow * HDIM + col]);
        hv = *reinterpret_cast<const float4*>(&A1[(size_t)grow * HDIM + col]);
        av.x *= inv; av.y *= inv; av.z *= inv; av.w *= inv;
      }
    }
    *reinterpret_cast<float4*>(&sA[row][col]) = av;
    *reinterpret_cast<float4*>(&sH[row][col]) = hv;
  }
  __syncthreads();

  const int c = t & 31;
  const int rg = t >> 5;
  float4 acc[4];
#pragma unroll
  for (int i = 0; i < 4; ++i) acc[i] = make_float4(0.f, 0.f, 0.f, 0.f);

  const float* wnp = Wn + c * 4;
  const float* wsp = Ws + c * 4;
#pragma unroll 8
  for (int k = 0; k < 128; ++k) {
    float4 wn = *reinterpret_cast<const float4*>(&wnp[(size_t)k * HDIM]);
    float4 wv = *reinterpret_cast<const float4*>(&wsp[(size_t)k * HDIM]);
#pragma unroll
    for (int i = 0; i < 4; ++i) {
      float a = sA[rg * 4 + i][k];
      float hh = sH[rg * 4 + i][k];
      acc[i].x += a * wn.x + hh * wv.x;
      acc[i].y += a * wn.y + hh * wv.y;
      acc[i].z += a * wn.z + hh * wv.z;
      acc[i].w += a * wn.w + hh * wv.w;
    }
  }

  float4 we0 = *reinterpret_cast<const float4*>(&Wn[(size_t)128 * HDIM + c * 4]);
  float4 we1 = *reinterpret_cast<const float4*>(&Wn[(size_t)129 * HDIM + c * 4]);
  float4 ps = make_float4(0.f, 0.f, 0.f, 0.f);
  float4 pq = make_float4(0.f, 0.f, 0.f, 0.f);
#pragma unroll
  for (int i = 0; i < 4; ++i) {
    int row = base + rg * 4 + i;
    if (row < N) {
      float inv = 1.0f / ((float)cnt[row] + 1.0f);
      float e0 = eagg[2 * (size_t)row + 0] * inv;
      float e1 = eagg[2 * (size_t)row + 1] * inv;
      float4 v;
      v.x = fmaxf(acc[i].x + e0 * we0.x + e1 * we1.x, 0.f);
      v.y = fmaxf(acc[i].y + e0 * we0.y + e1 * we1.y, 0.f);
      v.z = fmaxf(acc[i].z + e0 * we0.z + e1 * we1.z, 0.f);
      v.w = fmaxf(acc[i].w + e0 * we0.w + e1 * we1.w, 0.f);
      *reinterpret_cast<float4*>(&out[(size_t)row * HDIM + c * 4]) = v;
      ps.x += v.x; ps.y += v.y; ps.z += v.z; ps.w += v.w;
      pq.x += v.x * v.x; pq.y += v.y * v.y; pq.z += v.z * v.z; pq.w += v.w * v.w;
    }
  }

  __syncthreads();
  float* sp = &sA[0][0];
  float* sq = &sH[0][0];
  *reinterpret_cast<float4*>(&sp[rg * 128 + c * 4]) = ps;
  *reinterpret_cast<float4*>(&sq[rg * 128 + c * 4]) = pq;
  __syncthreads();
  if (t < 128) {
    float s = 0.f, s2 = 0.f;
#pragma unroll
    for (int rr = 0; rr < 8; ++rr) {
      s += sp[rr * 128 + t];
      s2 += sq[rr * 128 + t];
    }
    atomicAdd(&bnstat[t], s);
    atomicAdd(&bnstat[128 + t], s2);
  }
}

// --- BN finalize -----------------------------------------------------------
__global__ void bn_finalize_kernel(const float* __restrict__ stat,
                                   const float* __restrict__ gamma,
                                   const float* __restrict__ beta,
                                   float* __restrict__ ab, float invN) {
  int j = threadIdx.x;
  float mean = stat[j] * invN;
  float var = stat[128 + j] * invN - mean * mean;
  float inv = 1.0f / sqrtf(var + 1e-5f);
  float A = inv * gamma[j];
  ab[j] = A;
  ab[128 + j] = beta[j] - mean * A;
}

// --- BN apply + L2 normalize (in place), 1 wave per node -------------------
__global__ __launch_bounds__(64) void bn_l2_kernel(float* __restrict__ h,
                                                   const float* __restrict__ ab,
                                                   int N) {
  int i = blockIdx.x;
  if (i >= N) return;
  int lane = threadIdx.x;
  size_t off = (size_t)i * HDIM + lane * 2;
  float2 v = *reinterpret_cast<const float2*>(&h[off]);
  float A0 = ab[lane * 2 + 0], A1 = ab[lane * 2 + 1];
  float B0 = ab[128 + lane * 2 + 0], B1 = ab[128 + lane * 2 + 1];
  float y0 = v.x * A0 + B0;
  float y1 = v.y * A1 + B1;
  float s = y0 * y0 + y1 * y1;
#pragma unroll
  for (int m = 32; m > 0; m >>= 1) s += __shfl_xor(s, m, 64);
  float nrm = fmaxf(sqrtf(s), 1e-12f);
  float inv = 1.0f / nrm;
  float2 o;
  o.x = y0 * inv;
  o.y = y1 * inv;
  *reinterpret_cast<float2*>(&h[off]) = o;
}

// --- jump concat @ W_jump + relu + scorer MLP (3 K-phases, 24KB LDS) -------
__global__ __launch_bounds__(256) void jump_score_kernel(
    const float* __restrict__ h1, const float* __restrict__ h2,
    const float* __restrict__ h3, const float* __restrict__ Wj,
    const float* __restrict__ bj, const float* __restrict__ W1p,
    const float* __restrict__ b1p, const float* __restrict__ W2p,
    const float* __restrict__ b2p, float* __restrict__ outp, int N) {
  __shared__ float sA[32 * 128];  // 16KB staging, reused as sG
  __shared__ float sS[32 * 64];   // 8KB scorer hidden
  const int t = threadIdx.x;
  const int base = blockIdx.x * 32;
  const int c = t & 31, rg = t >> 5;

  float4 acc[4];
#pragma unroll
  for (int i = 0; i < 4; ++i) acc[i] = make_float4(0.f, 0.f, 0.f, 0.f);

  const float* hs[3] = {h1, h2, h3};
  for (int l = 0; l < 3; ++l) {
#pragma unroll
    for (int it = 0; it < 4; ++it) {
      int m = t * 4 + it * 1024;
      int row = m >> 7, col = m & 127;
      int grow = base + row;
      float4 v = make_float4(0.f, 0.f, 0.f, 0.f);
      if (grow < N) v = *reinterpret_cast<const float4*>(&hs[l][(size_t)grow * HDIM + col]);
      *reinterpret_cast<float4*>(&sA[row * 128 + col]) = v;
    }
    __syncthreads();
    const float* wp = Wj + (size_t)l * 128 * HDIM + c * 4;
#pragma unroll 8
    for (int k = 0; k < 128; ++k) {
      float4 w = *reinterpret_cast<const float4*>(&wp[(size_t)k * HDIM]);
#pragma unroll
      for (int i = 0; i < 4; ++i) {
        float a = sA[(rg * 4 + i) * 128 + k];
        acc[i].x += a * w.x;
        acc[i].y += a * w.y;
        acc[i].z += a * w.z;
        acc[i].w += a * w.w;
      }
    }
    __syncthreads();
  }

  float4 bb = *reinterpret_cast<const float4*>(&bj[c * 4]);
  float* sG = sA;
#pragma unroll
  for (int i = 0; i < 4; ++i) {
    float4 g;
    g.x = fmaxf(acc[i].x + bb.x, 0.f);
    g.y = fmaxf(acc[i].y + bb.y, 0.f);
    g.z = fmaxf(acc[i].z + bb.z, 0.f);
    g.w = fmaxf(acc[i].w + bb.w, 0.f);
    *reinterpret_cast<float4*>(&sG[(rg * 4 + i) * 128 + c * 4]) = g;
  }
  __syncthreads();

  // scorer layer 1: s1[row][m] = relu(b1[m] + g[row] . W1[:,m]), m<64
  const int m = t & 63, g4 = t >> 6;
  float a2[8];
#pragma unroll
  for (int i = 0; i < 8; ++i) a2[i] = b1p[m];
#pragma unroll 4
  for (int k = 0; k < 128; ++k) {
    float w = W1p[(size_t)k * 64 + m];
#pragma unroll
    for (int i = 0; i < 8; ++i) a2[i] += sG[(g4 * 8 + i) * 128 + k] * w;
  }
#pragma unroll
  for (int i = 0; i < 8; ++i) sS[(g4 * 8 + i) * 64 + m] = fmaxf(a2[i], 0.f);
  __syncthreads();

  if (t < 32) {
    int row = base + t;
    if (row < N) {
      float s = b2p[0];
#pragma unroll 8
      for (int mm = 0; mm < 64; ++mm) s += sS[t * 64 + mm] * W2p[mm];
      outp[row] = s;
    }
  }
}

// ---------------------------------------------------------------------------
extern "C" void kernel_launch(void* const* d_in, const int* in_sizes, int n_in,
                              void* d_out, int out_size, void* d_ws, size_t ws_size,
                              hipStream_t stream) {
  const float* x      = (const float*)d_in[0];
  const int*   ei     = (const int*)d_in[1];
  const float* eattr  = (const float*)d_in[2];
  const float* W_in   = (const float*)d_in[3];
  const float* b_in   = (const float*)d_in[4];
  const float* W_jump = (const float*)d_in[5];
  const float* b_jump = (const float*)d_in[6];
  const float* W1     = (const float*)d_in[7];
  const float* b1     = (const float*)d_in[8];
  const float* W2     = (const float*)d_in[9];
  const float* b2     = (const float*)d_in[10];
  const float* Wn[3] = {(const float*)d_in[11], (const float*)d_in[15], (const float*)d_in[19]};
  const float* Ws[3] = {(const float*)d_in[12], (const float*)d_in[16], (const float*)d_in[20]};
  const float* gm[3] = {(const float*)d_in[13], (const float*)d_in[17], (const float*)d_in[21]};
  const float* bt[3] = {(const float*)d_in[14], (const float*)d_in[18], (const float*)d_in[22]};

  const int N = in_sizes[0] / 4;
  const int E = in_sizes[2] / 2;
  const int* srcp = ei;
  const int* dstp = ei + (size_t)E;
  const int nch = (N + 127) / 128;

  const size_t nh = (size_t)N * HDIM;
  float* ws = (float*)d_ws;
  float* h1   = ws;
  float* h2   = h1 + nh;
  float* h3   = h2 + nh;
  float* agg  = h3 + nh;
  float* aggx = agg + nh;                 // 4N
  int*   cnt  = (int*)(aggx + 4 * (size_t)N);  // N  (memset with eagg below)
  float* eagg = (float*)(cnt + N);        // 2N
  int*   rowstart = (int*)(eagg + 2 * (size_t)N);  // N
  int*   rowcur   = rowstart + N;         // N
  int*   cidx     = rowcur + N;           // E
  int*   bsum     = cidx + E;             // <=1024
  int*   boff     = bsum + 1024;          // <=1024
  float* bnstat   = (float*)(boff + 1024);  // 256
  float* bnab     = bnstat + 256;           // 256

  // --- CSR build (layer-invariant) ---
  hipMemsetAsync(cnt, 0, 3 * (size_t)N * sizeof(int), stream);
  count_kernel<<<(E + 255) / 256, 256, 0, stream>>>(dstp, eattr, cnt, eagg, E);
  scan_block_sum<<<nch, 128, 0, stream>>>(cnt, bsum, N);
  scan_partials<<<1, 256, 0, stream>>>(bsum, boff, nch);
  scan_final<<<nch, 128, 0, stream>>>(cnt, boff, rowstart, rowcur, N);
  fill_kernel<<<(E + 255) / 256, 256, 0, stream>>>(srcp, dstp, rowcur, cidx, E);
  // note: after fill, rowcur[i] == row end

  // --- layer 0 (aggregation folded into x-space) ---
  aggx_kernel<<<(N + 255) / 256, 256, 0, stream>>>(x, rowstart, rowcur, cidx, aggx, N);
  hipMemsetAsync(bnstat, 0, 256 * sizeof(float), stream);
  sage_gemm_kernel<true><<<(N + 31) / 32, 256, 0, stream>>>(
      aggx, x, W_in, b_in, eagg, cnt, Wn[0], Ws[0], h1, bnstat, N);
  bn_finalize_kernel<<<1, 128, 0, stream>>>(bnstat, gm[0], bt[0], bnab, 1.0f / (float)N);
  bn_l2_kernel<<<N, 64, 0, stream>>>(h1, bnab, N);

  // --- layers 1,2 ---
  float* hbuf[3] = {h1, h2, h3};
  for (int l = 1; l < 3; ++l) {
    csr_agg_kernel<<<(N + 3) / 4, 256, 0, stream>>>(hbuf[l - 1], rowstart, rowcur, cidx, agg, N);
    hipMemsetAsync(bnstat, 0, 256 * sizeof(float), stream);
    sage_gemm_kernel<false><<<(N + 31) / 32, 256, 0, stream>>>(
        agg, hbuf[l - 1], nullptr, nullptr, eagg, cnt, Wn[l], Ws[l], hbuf[l], bnstat, N);
    bn_finalize_kernel<<<1, 128, 0, stream>>>(bnstat, gm[l], bt[l], bnab, 1.0f / (float)N);
    bn_l2_kernel<<<N, 64, 0, stream>>>(hbuf[l], bnab, N);
  }

  jump_score_kernel<<<(N + 31) / 32, 256, 0, stream>>>(h1, h2, h3, W_jump, b_jump,
                                                       W1, b1, W2, b2, (float*)d_out, N);
}

// Round 3
// 972.721 us; speedup vs baseline: 9.6159x; 1.5316x over previous
//
#include <hip/hip_runtime.h>

// ---------------------------------------------------------------------------
// GNN forward (GraphSAGE x3 + jump + scorer), N=100000, E=1600000, H=128.
// Round 3: layer + jump GEMMs on MFMA (f16 inputs, f32 accumulate).
//   A = [agg*inv | h_prev]  (N x 256)  @  B = [Wn(0:128); Ws]  (256 x 128)
// Edge-attr rank-2 update, BN, L2-norm stay in exact f32.
// ---------------------------------------------------------------------------

#define HDIM 128

using f16x8 = __attribute__((ext_vector_type(8))) _Float16;
using f32x4 = __attribute__((ext_vector_type(4))) float;

// --- per-edge count + edge-attr aggregation (layer-invariant) --------------
__global__ __launch_bounds__(256) void count_kernel(
    const int* __restrict__ dst, const float* __restrict__ ea,
    int* __restrict__ cnt, float* __restrict__ eagg, int E) {
  int e = blockIdx.x * 256 + threadIdx.x;
  if (e >= E) return;
  int d = dst[e];
  atomicAdd(&cnt[d], 1);
  float2 v = *reinterpret_cast<const float2*>(&ea[2 * (size_t)e]);
  atomicAdd(&eagg[2 * (size_t)d + 0], v.x);
  atomicAdd(&eagg[2 * (size_t)d + 1], v.y);
}

// --- scan stage A: per-128-chunk sums --------------------------------------
__global__ __launch_bounds__(128) void scan_block_sum(
    const int* __restrict__ cnt, int* __restrict__ bsum, int N) {
  __shared__ int sd[128];
  int t = threadIdx.x;
  int i = blockIdx.x * 128 + t;
  sd[t] = (i < N) ? cnt[i] : 0;
  __syncthreads();
  for (int off = 64; off > 0; off >>= 1) {
    if (t < off) sd[t] += sd[t + off];
    __syncthreads();
  }
  if (t == 0) bsum[blockIdx.x] = sd[0];
}

// --- scan stage B: exclusive scan of chunk sums (nch <= 1024) --------------
__global__ __launch_bounds__(256) void scan_partials(
    const int* __restrict__ bsum, int* __restrict__ boff, int nch) {
  __shared__ int sd[256];
  int t = threadIdx.x;
  int base = t * 4;
  int v0 = (base + 0 < nch) ? bsum[base + 0] : 0;
  int v1 = (base + 1 < nch) ? bsum[base + 1] : 0;
  int v2 = (base + 2 < nch) ? bsum[base + 2] : 0;
  int v3 = (base + 3 < nch) ? bsum[base + 3] : 0;
  sd[t] = v0 + v1 + v2 + v3;
  __syncthreads();
  for (int off = 1; off < 256; off <<= 1) {
    int x = sd[t];
    int y = (t >= off) ? sd[t - off] : 0;
    __syncthreads();
    sd[t] = x + y;
    __syncthreads();
  }
  int run = (t == 0) ? 0 : sd[t - 1];
  if (base + 0 < nch) boff[base + 0] = run; run += v0;
  if (base + 1 < nch) boff[base + 1] = run; run += v1;
  if (base + 2 < nch) boff[base + 2] = run; run += v2;
  if (base + 3 < nch) boff[base + 3] = run;
}

// --- scan stage C: per-element exclusive offsets -> rowstart, rowcur -------
__global__ __launch_bounds__(128) void scan_final(
    const int* __restrict__ cnt, const int* __restrict__ boff,
    int* __restrict__ rs, int* __restrict__ rc, int N) {
  __shared__ int sd[128];
  int t = threadIdx.x, b = blockIdx.x;
  int i = b * 128 + t;
  int v = (i < N) ? cnt[i] : 0;
  sd[t] = v;
  __syncthreads();
  for (int off = 1; off < 128; off <<= 1) {
    int x = sd[t];
    int y = (t >= off) ? sd[t - off] : 0;
    __syncthreads();
    sd[t] = x + y;
    __syncthreads();
  }
  int excl = boff[b] + ((t == 0) ? 0 : sd[t - 1]);
  if (i < N) { rs[i] = excl; rc[i] = excl; }
}

// --- CSR fill: cidx grouped by dst (order within a row irrelevant) ---------
__global__ __launch_bounds__(256) void fill_kernel(
    const int* __restrict__ src, const int* __restrict__ dst,
    int* __restrict__ rc, int* __restrict__ cidx, int E) {
  int e = blockIdx.x * 256 + threadIdx.x;
  if (e >= E) return;
  int d = dst[e];
  int pos = atomicAdd(&rc[d], 1);
  cidx[pos] = src[e];
}

// --- layer-0 aggregation in x-space (4 floats/node, incl self) -------------
__global__ __launch_bounds__(256) void aggx_kernel(
    const float* __restrict__ x, const int* __restrict__ rs,
    const int* __restrict__ re, const int* __restrict__ cidx,
    float* __restrict__ aggx, int N) {
  int i = blockIdx.x * 256 + threadIdx.x;
  if (i >= N) return;
  float4 a = *reinterpret_cast<const float4*>(&x[(size_t)i * 4]);
  float4 b = make_float4(0.f, 0.f, 0.f, 0.f);
  int p = rs[i], e = re[i];
  for (; p + 1 < e; p += 2) {
    int s0 = cidx[p], s1 = cidx[p + 1];
    float4 v0 = *reinterpret_cast<const float4*>(&x[(size_t)s0 * 4]);
    float4 v1 = *reinterpret_cast<const float4*>(&x[(size_t)s1 * 4]);
    a.x += v0.x; a.y += v0.y; a.z += v0.z; a.w += v0.w;
    b.x += v1.x; b.y += v1.y; b.z += v1.z; b.w += v1.w;
  }
  if (p < e) {
    int s = cidx[p];
    float4 v = *reinterpret_cast<const float4*>(&x[(size_t)s * 4]);
    a.x += v.x; a.y += v.y; a.z += v.z; a.w += v.w;
  }
  a.x += b.x; a.y += b.y; a.z += b.z; a.w += b.w;
  *reinterpret_cast<float4*>(&aggx[(size_t)i * 4]) = a;
}

// --- layers 1,2 aggregation: one wave per node, float2 per lane ------------
__global__ __launch_bounds__(256) void csr_agg_kernel(
    const float* __restrict__ h, const int* __restrict__ rs,
    const int* __restrict__ re, const int* __restrict__ cidx,
    float* __restrict__ agg, int N) {
  int i = blockIdx.x * 4 + (threadIdx.x >> 6);
  if (i >= N) return;
  int lane = threadIdx.x & 63;
  const float* hb = h + (size_t)lane * 2;
  float2 a0 = *reinterpret_cast<const float2*>(&hb[(size_t)i * HDIM]);  // self
  float2 a1 = make_float2(0.f, 0.f), a2 = make_float2(0.f, 0.f), a3 = make_float2(0.f, 0.f);
  int p = rs[i], e = re[i];
  for (; p + 3 < e; p += 4) {
    int s0 = cidx[p], s1 = cidx[p + 1], s2 = cidx[p + 2], s3 = cidx[p + 3];
    float2 v0 = *reinterpret_cast<const float2*>(&hb[(size_t)s0 * HDIM]);
    float2 v1 = *reinterpret_cast<const float2*>(&hb[(size_t)s1 * HDIM]);
    float2 v2 = *reinterpret_cast<const float2*>(&hb[(size_t)s2 * HDIM]);
    float2 v3 = *reinterpret_cast<const float2*>(&hb[(size_t)s3 * HDIM]);
    a0.x += v0.x; a0.y += v0.y;
    a1.x += v1.x; a1.y += v1.y;
    a2.x += v2.x; a2.y += v2.y;
    a3.x += v3.x; a3.y += v3.y;
  }
  for (; p < e; ++p) {
    int s = cidx[p];
    float2 v = *reinterpret_cast<const float2*>(&hb[(size_t)s * HDIM]);
    a0.x += v.x; a0.y += v.y;
  }
  a0.x += a1.x + a2.x + a3.x;
  a0.y += a1.y + a2.y + a3.y;
  *reinterpret_cast<float2*>(&agg[(size_t)i * HDIM + lane * 2]) = a0;
}

// --- pack GEMM weights into MFMA-frag-contiguous f16 layout ----------------
// sage layer l: B = [Wn_l rows 0..127 ; Ws_l] (256x128), 8 kt x 8 nt.
//   elem index ((kt*8+nt)*64 + lane)*8 + j  <-  B[kt*32+(lane>>4)*8+j][nt*16+(lane&15)]
// jump: B = Wj (384x128), 12 kt x 8 nt, at offset 98304.
__global__ __launch_bounds__(256) void pack_weights_kernel(
    const float* __restrict__ Wn0, const float* __restrict__ Ws0,
    const float* __restrict__ Wn1, const float* __restrict__ Ws1,
    const float* __restrict__ Wn2, const float* __restrict__ Ws2,
    const float* __restrict__ Wj, _Float16* __restrict__ outp) {
  int i = blockIdx.x * 256 + threadIdx.x;
  if (i >= 147456) return;
  int j = i & 7, lane = (i >> 3) & 63;
  float v;
  if (i < 98304) {
    int l = i >> 15;
    int r = i & 32767;
    int nt = (r >> 9) & 7, kt = r >> 12;
    int k = kt * 32 + (lane >> 4) * 8 + j;
    int n = nt * 16 + (lane & 15);
    const float* Wn = (l == 0) ? Wn0 : (l == 1) ? Wn1 : Wn2;
    const float* Ws = (l == 0) ? Ws0 : (l == 1) ? Ws1 : Ws2;
    v = (k < 128) ? Wn[(size_t)k * HDIM + n] : Ws[(size_t)(k - 128) * HDIM + n];
  } else {
    int r = i - 98304;
    int nt = (r >> 9) & 7, kt = r >> 12;  // kt 0..11
    int k = kt * 32 + (lane >> 4) * 8 + j;
    int n = nt * 16 + (lane & 15);
    v = Wj[(size_t)k * HDIM + n];
  }
  outp[i] = (_Float16)v;
}

// --- fused SAGE layer on MFMA ----------------------------------------------
// Block: 64 rows, 4 waves; wave w owns rows w*16..w*16+15, all 128 cols.
// L0: A = [ (aggx*inv)@Wi + bi | x@Wi + bi ]; else A = [ agg*inv | h_prev ].
// out = relu(A@B + (eagg*inv) x Wn[128:130]); BN sum/sumsq accumulated.
template <bool L0>
__global__ __launch_bounds__(256) void sage_mfma_kernel(
    const float* __restrict__ A0, const float* __restrict__ A1,
    const float* __restrict__ Wi, const float* __restrict__ bi,
    const float* __restrict__ eagg, const int* __restrict__ cnt,
    const _Float16* __restrict__ Bp, const float* __restrict__ Wn,
    float* __restrict__ out, float* __restrict__ bnstat, int N) {
  __shared__ _Float16 sA[64 * 256];  // 32 KB, XOR-swizzled rows
  __shared__ float sE[128];          // e0,e1 per row (pre-scaled)
  __shared__ float sBNs[4][128];
  __shared__ float sBNq[4][128];
  const int t = threadIdx.x;
  const int base = blockIdx.x * 64;

  if (t < 64) {
    int grow = base + t;
    float e0 = 0.f, e1 = 0.f;
    if (grow < N) {
      float inv = 1.0f / ((float)cnt[grow] + 1.0f);
      e0 = eagg[2 * (size_t)grow] * inv;
      e1 = eagg[2 * (size_t)grow + 1] * inv;
    }
    sE[2 * t] = e0;
    sE[2 * t + 1] = e1;
  }

  // stage A tile: 64 rows x 256 k, f16, swizzle byte ^= (row&7)<<4
#pragma unroll
  for (int it = 0; it < 8; ++it) {
    int c = t + it * 256;
    int row = c >> 5, k8 = c & 31;
    int grow = base + row;
    float v[8] = {0.f, 0.f, 0.f, 0.f, 0.f, 0.f, 0.f, 0.f};
    if (grow < N) {
      float inv = 1.0f / ((float)cnt[grow] + 1.0f);
      if (L0) {
        float scale = (k8 < 16) ? inv : 1.0f;
        const float* rp = (k8 < 16) ? &A0[(size_t)grow * 4] : &A1[(size_t)grow * 4];
        float4 r = *reinterpret_cast<const float4*>(rp);
        int col0 = (k8 & 15) * 8;
#pragma unroll
        for (int jj = 0; jj < 8; ++jj) {
          int col = col0 + jj;
          v[jj] = bi[col] + scale * (r.x * Wi[col] + r.y * Wi[HDIM + col] +
                                     r.z * Wi[2 * HDIM + col] + r.w * Wi[3 * HDIM + col]);
        }
      } else {
        float scale;
        const float* p;
        if (k8 < 16) {
          scale = inv;
          p = &A0[(size_t)grow * HDIM + k8 * 8];
        } else {
          scale = 1.0f;
          p = &A1[(size_t)grow * HDIM + (k8 - 16) * 8];
        }
        float4 u0 = *reinterpret_cast<const float4*>(p);
        float4 u1 = *reinterpret_cast<const float4*>(p + 4);
        v[0] = u0.x * scale; v[1] = u0.y * scale; v[2] = u0.z * scale; v[3] = u0.w * scale;
        v[4] = u1.x * scale; v[5] = u1.y * scale; v[6] = u1.z * scale; v[7] = u1.w * scale;
      }
    }
    f16x8 hv;
#pragma unroll
    for (int jj = 0; jj < 8; ++jj) hv[jj] = (_Float16)v[jj];
    int byte = (row * 512 + k8 * 16) ^ ((row & 7) << 4);
    *reinterpret_cast<f16x8*>(reinterpret_cast<char*>(sA) + byte) = hv;
  }
  __syncthreads();

  const int lane = t & 63;
  const int w = t >> 6;
  const int col16 = lane & 15;
  const int kgrp = lane >> 4;
  f32x4 acc[8];
#pragma unroll
  for (int nt = 0; nt < 8; ++nt) acc[nt] = (f32x4){0.f, 0.f, 0.f, 0.f};

  const int arow = w * 16 + col16;
  const int aswz = (arow & 7) << 4;
#pragma unroll
  for (int kt = 0; kt < 8; ++kt) {
    int abyte = (arow * 512 + kt * 64 + kgrp * 16) ^ aswz;
    f16x8 a = *reinterpret_cast<const f16x8*>(reinterpret_cast<const char*>(sA) + abyte);
    const f16x8* bp = reinterpret_cast<const f16x8*>(Bp) + (size_t)kt * 512 + lane;
#pragma unroll
    for (int nt = 0; nt < 8; ++nt) {
      f16x8 b = bp[nt * 64];
      acc[nt] = __builtin_amdgcn_mfma_f32_16x16x32_f16(a, b, acc[nt], 0, 0, 0);
    }
  }

  // epilogue: edge-attr rank-2 update + relu + store + BN partials (f32)
#pragma unroll
  for (int nt = 0; nt < 8; ++nt) {
    int col = nt * 16 + col16;
    float we0 = Wn[(size_t)128 * HDIM + col];
    float we1 = Wn[(size_t)129 * HDIM + col];
    float s = 0.f, q = 0.f;
#pragma unroll
    for (int i = 0; i < 4; ++i) {
      int lr = w * 16 + kgrp * 4 + i;
      int row = base + lr;
      if (row < N) {
        float v = acc[nt][i] + sE[2 * lr] * we0 + sE[2 * lr + 1] * we1;
        v = fmaxf(v, 0.f);
        out[(size_t)row * HDIM + col] = v;
        s += v;
        q += v * v;
      }
    }
    s += __shfl_xor(s, 16, 64);
    s += __shfl_xor(s, 32, 64);
    q += __shfl_xor(q, 16, 64);
    q += __shfl_xor(q, 32, 64);
    if (lane < 16) {
      sBNs[w][col] = s;
      sBNq[w][col] = q;
    }
  }
  __syncthreads();
  if (t < 128) {
    float s = sBNs[0][t] + sBNs[1][t] + sBNs[2][t] + sBNs[3][t];
    float q = sBNq[0][t] + sBNq[1][t] + sBNq[2][t] + sBNq[3][t];
    atomicAdd(&bnstat[t], s);
    atomicAdd(&bnstat[HDIM + t], q);
  }
}

// --- BN finalize -----------------------------------------------------------
__global__ void bn_finalize_kernel(const float* __restrict__ stat,
                                   const float* __restrict__ gamma,
                                   const float* __restrict__ beta,
                                   float* __restrict__ ab, float invN) {
  int j = threadIdx.x;
  float mean = stat[j] * invN;
  float var = stat[128 + j] * invN - mean * mean;
  float inv = 1.0f / sqrtf(var + 1e-5f);
  float A = inv * gamma[j];
  ab[j] = A;
  ab[128 + j] = beta[j] - mean * A;
}

// --- BN apply + L2 normalize (in place), 1 wave per node -------------------
__global__ __launch_bounds__(64) void bn_l2_kernel(float* __restrict__ h,
                                                   const float* __restrict__ ab,
                                                   int N) {
  int i = blockIdx.x;
  if (i >= N) return;
  int lane = threadIdx.x;
  size_t off = (size_t)i * HDIM + lane * 2;
  float2 v = *reinterpret_cast<const float2*>(&h[off]);
  float A0 = ab[lane * 2 + 0], A1 = ab[lane * 2 + 1];
  float B0 = ab[128 + lane * 2 + 0], B1 = ab[128 + lane * 2 + 1];
  float y0 = v.x * A0 + B0;
  float y1 = v.y * A1 + B1;
  float s = y0 * y0 + y1 * y1;
#pragma unroll
  for (int m = 32; m > 0; m >>= 1) s += __shfl_xor(s, m, 64);
  float nrm = fmaxf(sqrtf(s), 1e-12f);
  float inv = 1.0f / nrm;
  float2 o;
  o.x = y0 * inv;
  o.y = y1 * inv;
  *reinterpret_cast<float2*>(&h[off]) = o;
}

// --- jump GEMM (MFMA, K=384) + scorer MLP ----------------------------------
__global__ __launch_bounds__(256) void jump_mfma_kernel(
    const float* __restrict__ h1, const float* __restrict__ h2,
    const float* __restrict__ h3, const _Float16* __restrict__ Bp,
    const float* __restrict__ bj, const float* __restrict__ W1p,
    const float* __restrict__ b1p, const float* __restrict__ W2p,
    const float* __restrict__ b2p, float* __restrict__ outp, int N) {
  __shared__ _Float16 sA[64 * 384];  // 48 KB; reused: sG[64*128] f32 + sS[64*64] f32
  const int t = threadIdx.x;
  const int base = blockIdx.x * 64;

  // stage concat(h1,h2,h3) rows as f16, swizzled (row stride 768 B)
  const float* hs[3] = {h1, h2, h3};
#pragma unroll
  for (int it = 0; it < 12; ++it) {
    int c = t + it * 256;
    int row = c / 48, k8 = c % 48;
    int grow = base + row;
    float v[8] = {0.f, 0.f, 0.f, 0.f, 0.f, 0.f, 0.f, 0.f};
    if (grow < N) {
      const float* p = &hs[k8 >> 4][(size_t)grow * HDIM + (k8 & 15) * 8];
      float4 u0 = *reinterpret_cast<const float4*>(p);
      float4 u1 = *reinterpret_cast<const float4*>(p + 4);
      v[0] = u0.x; v[1] = u0.y; v[2] = u0.z; v[3] = u0.w;
      v[4] = u1.x; v[5] = u1.y; v[6] = u1.z; v[7] = u1.w;
    }
    f16x8 hv;
#pragma unroll
    for (int jj = 0; jj < 8; ++jj) hv[jj] = (_Float16)v[jj];
    int byte = (row * 768 + k8 * 16) ^ ((row & 7) << 4);
    *reinterpret_cast<f16x8*>(reinterpret_cast<char*>(sA) + byte) = hv;
  }
  __syncthreads();

  const int lane = t & 63;
  const int w = t >> 6;
  const int col16 = lane & 15;
  const int kgrp = lane >> 4;
  f32x4 acc[8];
#pragma unroll
  for (int nt = 0; nt < 8; ++nt) acc[nt] = (f32x4){0.f, 0.f, 0.f, 0.f};

  const int arow = w * 16 + col16;
  const int aswz = (arow & 7) << 4;
#pragma unroll
  for (int kt = 0; kt < 12; ++kt) {
    int abyte = (arow * 768 + kt * 64 + kgrp * 16) ^ aswz;
    f16x8 a = *reinterpret_cast<const f16x8*>(reinterpret_cast<const char*>(sA) + abyte);
    const f16x8* bp = reinterpret_cast<const f16x8*>(Bp) + (size_t)kt * 512 + lane;
#pragma unroll
    for (int nt = 0; nt < 8; ++nt) {
      f16x8 b = bp[nt * 64];
      acc[nt] = __builtin_amdgcn_mfma_f32_16x16x32_f16(a, b, acc[nt], 0, 0, 0);
    }
  }
  __syncthreads();  // all waves done reading sA -> safe to alias

  // g = relu(acc + bj) -> sG [64][128] f32
  float* sG = reinterpret_cast<float*>(sA);
  float* sS = sG + 64 * 128;
#pragma unroll
  for (int nt = 0; nt < 8; ++nt) {
    int col = nt * 16 + col16;
    float bb = bj[col];
#pragma unroll
    for (int i = 0; i < 4; ++i) {
      int lr = w * 16 + kgrp * 4 + i;
      sG[lr * 128 + col] = fmaxf(acc[nt][i] + bb, 0.f);
    }
  }
  __syncthreads();

  // scorer layer 1: 4 groups x 16 rows, m = t&63
  const int m = t & 63, grp = t >> 6;
  float a2[16];
#pragma unroll
  for (int i = 0; i < 16; ++i) a2[i] = b1p[m];
#pragma unroll 4
  for (int k = 0; k < 128; ++k) {
    float wv = W1p[(size_t)k * 64 + m];
#pragma unroll
    for (int i = 0; i < 16; ++i) a2[i] += sG[(grp * 16 + i) * 128 + k] * wv;
  }
#pragma unroll
  for (int i = 0; i < 16; ++i) sS[(grp * 16 + i) * 64 + m] = fmaxf(a2[i], 0.f);
  __syncthreads();

  if (t < 64) {
    int row = base + t;
    if (row < N) {
      float s = b2p[0];
#pragma unroll 8
      for (int mm = 0; mm < 64; ++mm) s += sS[t * 64 + mm] * W2p[mm];
      outp[row] = s;
    }
  }
}

// ---------------------------------------------------------------------------
extern "C" void kernel_launch(void* const* d_in, const int* in_sizes, int n_in,
                              void* d_out, int out_size, void* d_ws, size_t ws_size,
                              hipStream_t stream) {
  const float* x      = (const float*)d_in[0];
  const int*   ei     = (const int*)d_in[1];
  const float* eattr  = (const float*)d_in[2];
  const float* W_in   = (const float*)d_in[3];
  const float* b_in   = (const float*)d_in[4];
  const float* W_jump = (const float*)d_in[5];
  const float* b_jump = (const float*)d_in[6];
  const float* W1     = (const float*)d_in[7];
  const float* b1     = (const float*)d_in[8];
  const float* W2     = (const float*)d_in[9];
  const float* b2     = (const float*)d_in[10];
  const float* Wn[3] = {(const float*)d_in[11], (const float*)d_in[15], (const float*)d_in[19]};
  const float* Ws[3] = {(const float*)d_in[12], (const float*)d_in[16], (const float*)d_in[20]};
  const float* gm[3] = {(const float*)d_in[13], (const float*)d_in[17], (const float*)d_in[21]};
  const float* bt[3] = {(const float*)d_in[14], (const float*)d_in[18], (const float*)d_in[22]};

  const int N = in_sizes[0] / 4;
  const int E = in_sizes[2] / 2;
  const int* srcp = ei;
  const int* dstp = ei + (size_t)E;
  const int nch = (N + 127) / 128;

  const size_t nh = (size_t)N * HDIM;
  float* ws = (float*)d_ws;
  float* h1   = ws;
  float* h2   = h1 + nh;
  float* h3   = h2 + nh;
  float* agg  = h3 + nh;
  float* aggx = agg + nh;                      // 4N
  int*   cnt  = (int*)(aggx + 4 * (size_t)N);  // N
  float* eagg = (float*)(cnt + N);             // 2N
  int*   rowstart = (int*)(eagg + 2 * (size_t)N);  // N
  int*   rowcur   = rowstart + N;              // N
  int*   cidx     = rowcur + N;                // E
  int*   bsum     = cidx + E;                  // <=1024
  int*   boff     = bsum + 1024;               // <=1024
  float* bnstat   = (float*)(boff + 1024);     // 256
  float* bnab     = bnstat + 256;              // 256
  uintptr_t wp = (uintptr_t)(bnab + 256);
  wp = (wp + 15) & ~(uintptr_t)15;
  _Float16* wpack = (_Float16*)wp;             // 147456 f16 (~288 KB)

  // --- CSR build + weight pack (layer-invariant) ---
  hipMemsetAsync(cnt, 0, 3 * (size_t)N * sizeof(int), stream);
  count_kernel<<<(E + 255) / 256, 256, 0, stream>>>(dstp, eattr, cnt, eagg, E);
  pack_weights_kernel<<<(147456 + 255) / 256, 256, 0, stream>>>(
      Wn[0], Ws[0], Wn[1], Ws[1], Wn[2], Ws[2], W_jump, wpack);
  scan_block_sum<<<nch, 128, 0, stream>>>(cnt, bsum, N);
  scan_partials<<<1, 256, 0, stream>>>(bsum, boff, nch);
  scan_final<<<nch, 128, 0, stream>>>(cnt, boff, rowstart, rowcur, N);
  fill_kernel<<<(E + 255) / 256, 256, 0, stream>>>(srcp, dstp, rowcur, cidx, E);
  // note: after fill, rowcur[i] == row end

  const int gemm_grid = (N + 63) / 64;

  // --- layer 0 (aggregation folded into x-space) ---
  aggx_kernel<<<(N + 255) / 256, 256, 0, stream>>>(x, rowstart, rowcur, cidx, aggx, N);
  hipMemsetAsync(bnstat, 0, 256 * sizeof(float), stream);
  sage_mfma_kernel<true><<<gemm_grid, 256, 0, stream>>>(
      aggx, x, W_in, b_in, eagg, cnt, wpack, Wn[0], h1, bnstat, N);
  bn_finalize_kernel<<<1, 128, 0, stream>>>(bnstat, gm[0], bt[0], bnab, 1.0f / (float)N);
  bn_l2_kernel<<<N, 64, 0, stream>>>(h1, bnab, N);

  // --- layers 1,2 ---
  float* hbuf[3] = {h1, h2, h3};
  for (int l = 1; l < 3; ++l) {
    csr_agg_kernel<<<(N + 3) / 4, 256, 0, stream>>>(hbuf[l - 1], rowstart, rowcur, cidx, agg, N);
    hipMemsetAsync(bnstat, 0, 256 * sizeof(float), stream);
    sage_mfma_kernel<false><<<gemm_grid, 256, 0, stream>>>(
        agg, hbuf[l - 1], nullptr, nullptr, eagg, cnt, wpack + (size_t)l * 32768,
        Wn[l], hbuf[l], bnstat, N);
    bn_finalize_kernel<<<1, 128, 0, stream>>>(bnstat, gm[l], bt[l], bnab, 1.0f / (float)N);
    bn_l2_kernel<<<N, 64, 0, stream>>>(hbuf[l], bnab, N);
  }

  jump_mfma_kernel<<<gemm_grid, 256, 0, stream>>>(h1, h2, h3, wpack + 98304, b_jump,
                                                  W1, b1, W2, b2, (float*)d_out, N);
}

// Round 4
// 656.814 us; speedup vs baseline: 14.2408x; 1.4810x over previous
//
#include <hip/hip_runtime.h>

// ---------------------------------------------------------------------------
// GNN forward (GraphSAGE x3 + jump + scorer), N=100000, E=1600000, H=128.
// Round 4: 1 atomic/edge (cnt only); edge-attr rides in the CSR slot as f16x2;
// h stored f16 (halves gather traffic); csr_agg emits pre-scaled f16 mean.
// ---------------------------------------------------------------------------

#define HDIM 128

using f16x8 = __attribute__((ext_vector_type(8))) _Float16;
using f16x4 = __attribute__((ext_vector_type(4))) _Float16;
using f32x4 = __attribute__((ext_vector_type(4))) float;

__device__ inline unsigned pack_f16x2(float a, float b) {
  _Float16 ha = (_Float16)a, hb = (_Float16)b;
  unsigned short ua = __builtin_bit_cast(unsigned short, ha);
  unsigned short ub = __builtin_bit_cast(unsigned short, hb);
  return (unsigned)ua | ((unsigned)ub << 16);
}
__device__ inline float2 unpack_f16x2(unsigned u) {
  _Float16 lo = __builtin_bit_cast(_Float16, (unsigned short)(u & 0xffffu));
  _Float16 hi = __builtin_bit_cast(_Float16, (unsigned short)(u >> 16));
  return make_float2((float)lo, (float)hi);
}

// --- in-degree count: ONE atomic per edge ----------------------------------
__global__ __launch_bounds__(256) void count_kernel(
    const int* __restrict__ dst, int* __restrict__ cnt, int E) {
  int e = blockIdx.x * 256 + threadIdx.x;
  if (e >= E) return;
  atomicAdd(&cnt[dst[e]], 1);
}

// --- scan stage A: per-128-chunk sums --------------------------------------
__global__ __launch_bounds__(128) void scan_block_sum(
    const int* __restrict__ cnt, int* __restrict__ bsum, int N) {
  __shared__ int sd[128];
  int t = threadIdx.x;
  int i = blockIdx.x * 128 + t;
  sd[t] = (i < N) ? cnt[i] : 0;
  __syncthreads();
  for (int off = 64; off > 0; off >>= 1) {
    if (t < off) sd[t] += sd[t + off];
    __syncthreads();
  }
  if (t == 0) bsum[blockIdx.x] = sd[0];
}

// --- scan stage B: exclusive scan of chunk sums (nch <= 1024) --------------
__global__ __launch_bounds__(256) void scan_partials(
    const int* __restrict__ bsum, int* __restrict__ boff, int nch) {
  __shared__ int sd[256];
  int t = threadIdx.x;
  int base = t * 4;
  int v0 = (base + 0 < nch) ? bsum[base + 0] : 0;
  int v1 = (base + 1 < nch) ? bsum[base + 1] : 0;
  int v2 = (base + 2 < nch) ? bsum[base + 2] : 0;
  int v3 = (base + 3 < nch) ? bsum[base + 3] : 0;
  sd[t] = v0 + v1 + v2 + v3;
  __syncthreads();
  for (int off = 1; off < 256; off <<= 1) {
    int x = sd[t];
    int y = (t >= off) ? sd[t - off] : 0;
    __syncthreads();
    sd[t] = x + y;
    __syncthreads();
  }
  int run = (t == 0) ? 0 : sd[t - 1];
  if (base + 0 < nch) boff[base + 0] = run; run += v0;
  if (base + 1 < nch) boff[base + 1] = run; run += v1;
  if (base + 2 < nch) boff[base + 2] = run; run += v2;
  if (base + 3 < nch) boff[base + 3] = run;
}

// --- scan stage C: per-element exclusive offsets -> rowstart, rowcur -------
__global__ __launch_bounds__(128) void scan_final(
    const int* __restrict__ cnt, const int* __restrict__ boff,
    int* __restrict__ rs, int* __restrict__ rc, int N) {
  __shared__ int sd[128];
  int t = threadIdx.x, b = blockIdx.x;
  int i = b * 128 + t;
  int v = (i < N) ? cnt[i] : 0;
  sd[t] = v;
  __syncthreads();
  for (int off = 1; off < 128; off <<= 1) {
    int x = sd[t];
    int y = (t >= off) ? sd[t - off] : 0;
    __syncthreads();
    sd[t] = x + y;
    __syncthreads();
  }
  int excl = boff[b] + ((t == 0) ? 0 : sd[t - 1]);
  if (i < N) { rs[i] = excl; rc[i] = excl; }
}

// --- CSR fill: slot = {src, f16x2(edge_attr)} (8 B) ------------------------
__global__ __launch_bounds__(256) void fill_kernel(
    const int* __restrict__ src, const int* __restrict__ dst,
    const float* __restrict__ ea, int* __restrict__ rc,
    uint2* __restrict__ cidx2, int E) {
  int e = blockIdx.x * 256 + threadIdx.x;
  if (e >= E) return;
  int d = dst[e];
  float2 v = *reinterpret_cast<const float2*>(&ea[2 * (size_t)e]);
  int pos = atomicAdd(&rc[d], 1);
  cidx2[pos] = make_uint2((unsigned)src[e], pack_f16x2(v.x, v.y));
}

// --- layer-0 x-space aggregation + edge-attr sum (one thread per node) -----
__global__ __launch_bounds__(256) void aggx_kernel(
    const float* __restrict__ x, const int* __restrict__ rs,
    const int* __restrict__ re, const uint2* __restrict__ cidx2,
    float* __restrict__ aggx, float* __restrict__ eagg, int N) {
  int i = blockIdx.x * 256 + threadIdx.x;
  if (i >= N) return;
  float4 a = *reinterpret_cast<const float4*>(&x[(size_t)i * 4]);
  float4 b = make_float4(0.f, 0.f, 0.f, 0.f);
  float e0 = 0.f, e1 = 0.f, f0 = 0.f, f1 = 0.f;
  int p = rs[i], e = re[i];
  for (; p + 1 < e; p += 2) {
    uint2 c0 = cidx2[p], c1 = cidx2[p + 1];
    float4 v0 = *reinterpret_cast<const float4*>(&x[(size_t)c0.x * 4]);
    float4 v1 = *reinterpret_cast<const float4*>(&x[(size_t)c1.x * 4]);
    float2 u0 = unpack_f16x2(c0.y);
    float2 u1 = unpack_f16x2(c1.y);
    a.x += v0.x; a.y += v0.y; a.z += v0.z; a.w += v0.w;
    b.x += v1.x; b.y += v1.y; b.z += v1.z; b.w += v1.w;
    e0 += u0.x; e1 += u0.y;
    f0 += u1.x; f1 += u1.y;
  }
  if (p < e) {
    uint2 c0 = cidx2[p];
    float4 v0 = *reinterpret_cast<const float4*>(&x[(size_t)c0.x * 4]);
    float2 u0 = unpack_f16x2(c0.y);
    a.x += v0.x; a.y += v0.y; a.z += v0.z; a.w += v0.w;
    e0 += u0.x; e1 += u0.y;
  }
  a.x += b.x; a.y += b.y; a.z += b.z; a.w += b.w;
  *reinterpret_cast<float4*>(&aggx[(size_t)i * 4]) = a;
  eagg[2 * (size_t)i + 0] = e0 + f0;
  eagg[2 * (size_t)i + 1] = e1 + f1;
}

// --- layers 1,2 aggregation: 32 lanes/node, f16 h, emits f16 mean ----------
__global__ __launch_bounds__(256) void csr_agg_kernel(
    const _Float16* __restrict__ h, const int* __restrict__ rs,
    const int* __restrict__ re, const uint2* __restrict__ cidx2,
    const int* __restrict__ cnt, _Float16* __restrict__ aggm, int N) {
  int i = blockIdx.x * 8 + (threadIdx.x >> 5);
  if (i >= N) return;
  int lane = threadIdx.x & 31;
  const f16x4* hb = reinterpret_cast<const f16x4*>(h) + lane;  // row stride 32
  f16x4 sv = hb[(size_t)i * 32];  // self
  float a0 = (float)sv[0], a1 = (float)sv[1], a2 = (float)sv[2], a3 = (float)sv[3];
  float b0 = 0.f, b1 = 0.f, b2 = 0.f, b3 = 0.f;
  float c0 = 0.f, c1 = 0.f, c2 = 0.f, c3 = 0.f;
  float d0 = 0.f, d1 = 0.f, d2 = 0.f, d3 = 0.f;
  int p = rs[i], e = re[i];
  for (; p + 3 < e; p += 4) {
    uint2 q0 = cidx2[p], q1 = cidx2[p + 1], q2 = cidx2[p + 2], q3 = cidx2[p + 3];
    f16x4 v0 = hb[(size_t)q0.x * 32];
    f16x4 v1 = hb[(size_t)q1.x * 32];
    f16x4 v2 = hb[(size_t)q2.x * 32];
    f16x4 v3 = hb[(size_t)q3.x * 32];
    a0 += (float)v0[0]; a1 += (float)v0[1]; a2 += (float)v0[2]; a3 += (float)v0[3];
    b0 += (float)v1[0]; b1 += (float)v1[1]; b2 += (float)v1[2]; b3 += (float)v1[3];
    c0 += (float)v2[0]; c1 += (float)v2[1]; c2 += (float)v2[2]; c3 += (float)v2[3];
    d0 += (float)v3[0]; d1 += (float)v3[1]; d2 += (float)v3[2]; d3 += (float)v3[3];
  }
  for (; p < e; ++p) {
    uint2 q0 = cidx2[p];
    f16x4 v0 = hb[(size_t)q0.x * 32];
    a0 += (float)v0[0]; a1 += (float)v0[1]; a2 += (float)v0[2]; a3 += (float)v0[3];
  }
  float inv = 1.0f / ((float)cnt[i] + 1.0f);
  f16x4 o;
  o[0] = (_Float16)((a0 + b0 + c0 + d0) * inv);
  o[1] = (_Float16)((a1 + b1 + c1 + d1) * inv);
  o[2] = (_Float16)((a2 + b2 + c2 + d2) * inv);
  o[3] = (_Float16)((a3 + b3 + c3 + d3) * inv);
  (reinterpret_cast<f16x4*>(aggm) + lane)[(size_t)i * 32] = o;
}

// --- pack GEMM weights into MFMA-frag-contiguous f16 layout ----------------
__global__ __launch_bounds__(256) void pack_weights_kernel(
    const float* __restrict__ Wn0, const float* __restrict__ Ws0,
    const float* __restrict__ Wn1, const float* __restrict__ Ws1,
    const float* __restrict__ Wn2, const float* __restrict__ Ws2,
    const float* __restrict__ Wj, _Float16* __restrict__ outp) {
  int i = blockIdx.x * 256 + threadIdx.x;
  if (i >= 147456) return;
  int j = i & 7, lane = (i >> 3) & 63;
  float v;
  if (i < 98304) {
    int l = i >> 15;
    int r = i & 32767;
    int nt = (r >> 9) & 7, kt = r >> 12;
    int k = kt * 32 + (lane >> 4) * 8 + j;
    int n = nt * 16 + (lane & 15);
    const float* Wn = (l == 0) ? Wn0 : (l == 1) ? Wn1 : Wn2;
    const float* Ws = (l == 0) ? Ws0 : (l == 1) ? Ws1 : Ws2;
    v = (k < 128) ? Wn[(size_t)k * HDIM + n] : Ws[(size_t)(k - 128) * HDIM + n];
  } else {
    int r = i - 98304;
    int nt = (r >> 9) & 7, kt = r >> 12;  // kt 0..11
    int k = kt * 32 + (lane >> 4) * 8 + j;
    int n = nt * 16 + (lane & 15);
    v = Wj[(size_t)k * HDIM + n];
  }
  outp[i] = (_Float16)v;
}

// --- fused SAGE layer on MFMA ----------------------------------------------
// Block: 64 rows, 4 waves; wave w owns rows w*16..w*16+15, all 128 cols.
// L0: A = [ (aggx*inv)@Wi + bi | x@Wi + bi ]  (f32 sources).
// else: A = [ aggm | h_prev ]                 (f16 sources, straight copy).
// out(f32) = relu(A@B + (eagg*inv) x Wn[128:130]); BN sum/sumsq accumulated.
template <bool L0>
__global__ __launch_bounds__(256) void sage_mfma_kernel(
    const float* __restrict__ A0f, const float* __restrict__ A1f,
    const _Float16* __restrict__ A0h, const _Float16* __restrict__ A1h,
    const float* __restrict__ Wi, const float* __restrict__ bi,
    const float* __restrict__ eagg, const int* __restrict__ cnt,
    const _Float16* __restrict__ Bp, const float* __restrict__ Wn,
    float* __restrict__ out, float* __restrict__ bnstat, int N) {
  __shared__ _Float16 sA[64 * 256];  // 32 KB, XOR-swizzled rows
  __shared__ float sE[128];          // e0,e1 per row (pre-scaled)
  __shared__ float sBNs[4][128];
  __shared__ float sBNq[4][128];
  const int t = threadIdx.x;
  const int base = blockIdx.x * 64;

  if (t < 64) {
    int grow = base + t;
    float e0 = 0.f, e1 = 0.f;
    if (grow < N) {
      float inv = 1.0f / ((float)cnt[grow] + 1.0f);
      e0 = eagg[2 * (size_t)grow] * inv;
      e1 = eagg[2 * (size_t)grow + 1] * inv;
    }
    sE[2 * t] = e0;
    sE[2 * t + 1] = e1;
  }

  // stage A tile: 64 rows x 256 k, f16, swizzle byte ^= (row&7)<<4
#pragma unroll
  for (int it = 0; it < 8; ++it) {
    int c = t + it * 256;
    int row = c >> 5, k8 = c & 31;
    int grow = base + row;
    f16x8 hv = {};
    if (grow < N) {
      if (L0) {
        float inv = 1.0f / ((float)cnt[grow] + 1.0f);
        float scale = (k8 < 16) ? inv : 1.0f;
        const float* rp = (k8 < 16) ? &A0f[(size_t)grow * 4] : &A1f[(size_t)grow * 4];
        float4 r = *reinterpret_cast<const float4*>(rp);
        int col0 = (k8 & 15) * 8;
#pragma unroll
        for (int jj = 0; jj < 8; ++jj) {
          int col = col0 + jj;
          hv[jj] = (_Float16)(bi[col] + scale * (r.x * Wi[col] + r.y * Wi[HDIM + col] +
                                                 r.z * Wi[2 * HDIM + col] + r.w * Wi[3 * HDIM + col]));
        }
      } else {
        hv = (k8 < 16) ? (reinterpret_cast<const f16x8*>(A0h + (size_t)grow * HDIM))[k8]
                       : (reinterpret_cast<const f16x8*>(A1h + (size_t)grow * HDIM))[k8 - 16];
      }
    }
    int byte = (row * 512 + k8 * 16) ^ ((row & 7) << 4);
    *reinterpret_cast<f16x8*>(reinterpret_cast<char*>(sA) + byte) = hv;
  }
  __syncthreads();

  const int lane = t & 63;
  const int w = t >> 6;
  const int col16 = lane & 15;
  const int kgrp = lane >> 4;
  f32x4 acc[8];
#pragma unroll
  for (int nt = 0; nt < 8; ++nt) acc[nt] = (f32x4){0.f, 0.f, 0.f, 0.f};

  const int arow = w * 16 + col16;
  const int aswz = (arow & 7) << 4;
#pragma unroll
  for (int kt = 0; kt < 8; ++kt) {
    int abyte = (arow * 512 + kt * 64 + kgrp * 16) ^ aswz;
    f16x8 a = *reinterpret_cast<const f16x8*>(reinterpret_cast<const char*>(sA) + abyte);
    const f16x8* bp = reinterpret_cast<const f16x8*>(Bp) + (size_t)kt * 512 + lane;
#pragma unroll
    for (int nt = 0; nt < 8; ++nt) {
      f16x8 b = bp[nt * 64];
      acc[nt] = __builtin_amdgcn_mfma_f32_16x16x32_f16(a, b, acc[nt], 0, 0, 0);
    }
  }

  // epilogue: edge-attr rank-2 update + relu + store + BN partials (f32)
#pragma unroll
  for (int nt = 0; nt < 8; ++nt) {
    int col = nt * 16 + col16;
    float we0 = Wn[(size_t)128 * HDIM + col];
    float we1 = Wn[(size_t)129 * HDIM + col];
    float s = 0.f, q = 0.f;
#pragma unroll
    for (int i = 0; i < 4; ++i) {
      int lr = w * 16 + kgrp * 4 + i;
      int row = base + lr;
      if (row < N) {
        float v = acc[nt][i] + sE[2 * lr] * we0 + sE[2 * lr + 1] * we1;
        v = fmaxf(v, 0.f);
        out[(size_t)row * HDIM + col] = v;
        s += v;
        q += v * v;
      }
    }
    s += __shfl_xor(s, 16, 64);
    s += __shfl_xor(s, 32, 64);
    q += __shfl_xor(q, 16, 64);
    q += __shfl_xor(q, 32, 64);
    if (lane < 16) {
      sBNs[w][col] = s;
      sBNq[w][col] = q;
    }
  }
  __syncthreads();
  if (t < 128) {
    float s = sBNs[0][t] + sBNs[1][t] + sBNs[2][t] + sBNs[3][t];
    float q = sBNq[0][t] + sBNq[1][t] + sBNq[2][t] + sBNq[3][t];
    atomicAdd(&bnstat[t], s);
    atomicAdd(&bnstat[HDIM + t], q);
  }
}

// --- BN finalize -----------------------------------------------------------
__global__ void bn_finalize_kernel(const float* __restrict__ stat,
                                   const float* __restrict__ gamma,
                                   const float* __restrict__ beta,
                                   float* __restrict__ ab, float invN) {
  int j = threadIdx.x;
  float mean = stat[j] * invN;
  float var = stat[128 + j] * invN - mean * mean;
  float inv = 1.0f / sqrtf(var + 1e-5f);
  float A = inv * gamma[j];
  ab[j] = A;
  ab[128 + j] = beta[j] - mean * A;
}

// --- BN apply + L2 normalize: read f32 out, write f16 h --------------------
__global__ __launch_bounds__(256) void bn_l2_kernel(const float* __restrict__ outb,
                                                    const float* __restrict__ ab,
                                                    _Float16* __restrict__ h, int N) {
  int i = blockIdx.x * 4 + (threadIdx.x >> 6);
  if (i >= N) return;
  int lane = threadIdx.x & 63;
  float2 v = (reinterpret_cast<const float2*>(outb + (size_t)i * HDIM))[lane];
  float A0 = ab[lane * 2 + 0], A1 = ab[lane * 2 + 1];
  float B0 = ab[128 + lane * 2 + 0], B1 = ab[128 + lane * 2 + 1];
  float y0 = v.x * A0 + B0;
  float y1 = v.y * A1 + B1;
  float s = y0 * y0 + y1 * y1;
#pragma unroll
  for (int m = 32; m > 0; m >>= 1) s += __shfl_xor(s, m, 64);
  float inv = 1.0f / fmaxf(sqrtf(s), 1e-12f);
  (reinterpret_cast<unsigned*>(h + (size_t)i * HDIM))[lane] =
      pack_f16x2(y0 * inv, y1 * inv);
}

// --- jump GEMM (MFMA, K=384, f16 h inputs) + scorer MLP --------------------
__global__ __launch_bounds__(256) void jump_mfma_kernel(
    const _Float16* __restrict__ h1, const _Float16* __restrict__ h2,
    const _Float16* __restrict__ h3, const _Float16* __restrict__ Bp,
    const float* __restrict__ bj, const float* __restrict__ W1p,
    const float* __restrict__ b1p, const float* __restrict__ W2p,
    const float* __restrict__ b2p, float* __restrict__ outp, int N) {
  __shared__ _Float16 sA[64 * 384];  // 48 KB; reused: sG[64*128] f32 + sS[64*64] f32
  const int t = threadIdx.x;
  const int base = blockIdx.x * 64;

  const _Float16* hs[3] = {h1, h2, h3};
#pragma unroll
  for (int it = 0; it < 12; ++it) {
    int c = t + it * 256;
    int row = c / 48, k8 = c % 48;
    int grow = base + row;
    f16x8 hv = {};
    if (grow < N)
      hv = (reinterpret_cast<const f16x8*>(hs[k8 >> 4] + (size_t)grow * HDIM))[k8 & 15];
    int byte = (row * 768 + k8 * 16) ^ ((row & 7) << 4);
    *reinterpret_cast<f16x8*>(reinterpret_cast<char*>(sA) + byte) = hv;
  }
  __syncthreads();

  const int lane = t & 63;
  const int w = t >> 6;
  const int col16 = lane & 15;
  const int kgrp = lane >> 4;
  f32x4 acc[8];
#pragma unroll
  for (int nt = 0; nt < 8; ++nt) acc[nt] = (f32x4){0.f, 0.f, 0.f, 0.f};

  const int arow = w * 16 + col16;
  const int aswz = (arow & 7) << 4;
#pragma unroll
  for (int kt = 0; kt < 12; ++kt) {
    int abyte = (arow * 768 + kt * 64 + kgrp * 16) ^ aswz;
    f16x8 a = *reinterpret_cast<const f16x8*>(reinterpret_cast<const char*>(sA) + abyte);
    const f16x8* bp = reinterpret_cast<const f16x8*>(Bp) + (size_t)kt * 512 + lane;
#pragma unroll
    for (int nt = 0; nt < 8; ++nt) {
      f16x8 b = bp[nt * 64];
      acc[nt] = __builtin_amdgcn_mfma_f32_16x16x32_f16(a, b, acc[nt], 0, 0, 0);
    }
  }
  __syncthreads();  // all waves done reading sA -> safe to alias

  float* sG = reinterpret_cast<float*>(sA);
  float* sS = sG + 64 * 128;
#pragma unroll
  for (int nt = 0; nt < 8; ++nt) {
    int col = nt * 16 + col16;
    float bb = bj[col];
#pragma unroll
    for (int i = 0; i < 4; ++i) {
      int lr = w * 16 + kgrp * 4 + i;
      sG[lr * 128 + col] = fmaxf(acc[nt][i] + bb, 0.f);
    }
  }
  __syncthreads();

  const int m = t & 63, grp = t >> 6;
  float a2[16];
#pragma unroll
  for (int i = 0; i < 16; ++i) a2[i] = b1p[m];
#pragma unroll 4
  for (int k = 0; k < 128; ++k) {
    float wv = W1p[(size_t)k * 64 + m];
#pragma unroll
    for (int i = 0; i < 16; ++i) a2[i] += sG[(grp * 16 + i) * 128 + k] * wv;
  }
#pragma unroll
  for (int i = 0; i < 16; ++i) sS[(grp * 16 + i) * 64 + m] = fmaxf(a2[i], 0.f);
  __syncthreads();

  if (t < 64) {
    int row = base + t;
    if (row < N) {
      float s = b2p[0];
#pragma unroll 8
      for (int mm = 0; mm < 64; ++mm) s += sS[t * 64 + mm] * W2p[mm];
      outp[row] = s;
    }
  }
}

// ---------------------------------------------------------------------------
extern "C" void kernel_launch(void* const* d_in, const int* in_sizes, int n_in,
                              void* d_out, int out_size, void* d_ws, size_t ws_size,
                              hipStream_t stream) {
  const float* x      = (const float*)d_in[0];
  const int*   ei     = (const int*)d_in[1];
  const float* eattr  = (const float*)d_in[2];
  const float* W_in   = (const float*)d_in[3];
  const float* b_in   = (const float*)d_in[4];
  const float* W_jump = (const float*)d_in[5];
  const float* b_jump = (const float*)d_in[6];
  const float* W1     = (const float*)d_in[7];
  const float* b1     = (const float*)d_in[8];
  const float* W2     = (const float*)d_in[9];
  const float* b2     = (const float*)d_in[10];
  const float* Wn[3] = {(const float*)d_in[11], (const float*)d_in[15], (const float*)d_in[19]};
  const float* Ws[3] = {(const float*)d_in[12], (const float*)d_in[16], (const float*)d_in[20]};
  const float* gm[3] = {(const float*)d_in[13], (const float*)d_in[17], (const float*)d_in[21]};
  const float* bt[3] = {(const float*)d_in[14], (const float*)d_in[18], (const float*)d_in[22]};

  const int N = in_sizes[0] / 4;
  const int E = in_sizes[2] / 2;
  const int* srcp = ei;
  const int* dstp = ei + (size_t)E;
  const int nch = (N + 127) / 128;
  const size_t nh = (size_t)N * HDIM;

  // --- workspace carve-up (256B aligned blocks) ---
  char* wsb = (char*)d_ws;
  size_t off = 0;
  auto carve = [&](size_t bytes) -> void* {
    void* p = wsb + off;
    off = (off + bytes + 255) & ~(size_t)255;
    return p;
  };
  _Float16* h1   = (_Float16*)carve(nh * 2);
  _Float16* h2   = (_Float16*)carve(nh * 2);
  _Float16* h3   = (_Float16*)carve(nh * 2);
  _Float16* aggm = (_Float16*)carve(nh * 2);
  float*    outb = (float*)carve(nh * 4);
  float*    aggx = (float*)carve((size_t)N * 4 * 4);
  float*    eagg = (float*)carve((size_t)N * 2 * 4);
  int*      cnt  = (int*)carve((size_t)N * 4);
  int*      rowstart = (int*)carve((size_t)N * 4);
  int*      rowcur   = (int*)carve((size_t)N * 4);
  uint2*    cidx2    = (uint2*)carve((size_t)E * 8);
  int*      bsum = (int*)carve(4096);
  int*      boff = (int*)carve(4096);
  float*    bnstat = (float*)carve(1024);
  float*    bnab   = (float*)carve(1024);
  _Float16* wpack  = (_Float16*)carve(147456 * 2);

  // --- CSR build + weight pack (layer-invariant) ---
  hipMemsetAsync(cnt, 0, (size_t)N * sizeof(int), stream);
  count_kernel<<<(E + 255) / 256, 256, 0, stream>>>(dstp, cnt, E);
  pack_weights_kernel<<<(147456 + 255) / 256, 256, 0, stream>>>(
      Wn[0], Ws[0], Wn[1], Ws[1], Wn[2], Ws[2], W_jump, wpack);
  scan_block_sum<<<nch, 128, 0, stream>>>(cnt, bsum, N);
  scan_partials<<<1, 256, 0, stream>>>(bsum, boff, nch);
  scan_final<<<nch, 128, 0, stream>>>(cnt, boff, rowstart, rowcur, N);
  fill_kernel<<<(E + 255) / 256, 256, 0, stream>>>(srcp, dstp, eattr, rowcur, cidx2, E);
  // after fill, rowcur[i] == row end

  const int gemm_grid = (N + 63) / 64;

  // --- layer 0 (aggregation folded into x-space; eagg computed here) ---
  aggx_kernel<<<(N + 255) / 256, 256, 0, stream>>>(x, rowstart, rowcur, cidx2, aggx, eagg, N);
  hipMemsetAsync(bnstat, 0, 256 * sizeof(float), stream);
  sage_mfma_kernel<true><<<gemm_grid, 256, 0, stream>>>(
      aggx, x, nullptr, nullptr, W_in, b_in, eagg, cnt, wpack, Wn[0], outb, bnstat, N);
  bn_finalize_kernel<<<1, 128, 0, stream>>>(bnstat, gm[0], bt[0], bnab, 1.0f / (float)N);
  bn_l2_kernel<<<(N + 3) / 4, 256, 0, stream>>>(outb, bnab, h1, N);

  // --- layers 1,2 ---
  _Float16* hbuf[3] = {h1, h2, h3};
  for (int l = 1; l < 3; ++l) {
    csr_agg_kernel<<<(N + 7) / 8, 256, 0, stream>>>(hbuf[l - 1], rowstart, rowcur, cidx2,
                                                    cnt, aggm, N);
    hipMemsetAsync(bnstat, 0, 256 * sizeof(float), stream);
    sage_mfma_kernel<false><<<gemm_grid, 256, 0, stream>>>(
        nullptr, nullptr, aggm, hbuf[l - 1], nullptr, nullptr, eagg, cnt,
        wpack + (size_t)l * 32768, Wn[l], outb, bnstat, N);
    bn_finalize_kernel<<<1, 128, 0, stream>>>(bnstat, gm[l], bt[l], bnab, 1.0f / (float)N);
    bn_l2_kernel<<<(N + 3) / 4, 256, 0, stream>>>(outb, bnab, hbuf[l], N);
  }

  jump_mfma_kernel<<<gemm_grid, 256, 0, stream>>>(h1, h2, h3, wpack + 98304, b_jump,
                                                  W1, b1, W2, b2, (float*)d_out, N);
}

// Round 5
// 590.660 us; speedup vs baseline: 15.8358x; 1.1120x over previous
//
#include <hip/hip_runtime.h>

// ---------------------------------------------------------------------------
// GNN forward (GraphSAGE x3 + jump + scorer), N=100000, E=1600000, H=128.
// Round 5: rank-based CSR fill (zero atomics in fill); neighbor gather fused
// into the sage MFMA staging (csr_agg eliminated); pre-BN f16 outputs;
// bn_finalize folded into bn_l2.
// ---------------------------------------------------------------------------

#define HDIM 128

using f16x8 = __attribute__((ext_vector_type(8))) _Float16;
using f32x4 = __attribute__((ext_vector_type(4))) float;

__device__ inline unsigned pack_f16x2(float a, float b) {
  _Float16 ha = (_Float16)a, hb = (_Float16)b;
  unsigned short ua = __builtin_bit_cast(unsigned short, ha);
  unsigned short ub = __builtin_bit_cast(unsigned short, hb);
  return (unsigned)ua | ((unsigned)ub << 16);
}
__device__ inline float2 unpack_f16x2(unsigned u) {
  _Float16 lo = __builtin_bit_cast(_Float16, (unsigned short)(u & 0xffffu));
  _Float16 hi = __builtin_bit_cast(_Float16, (unsigned short)(u >> 16));
  return make_float2((float)lo, (float)hi);
}

// --- in-degree count; atomic return value IS the edge's intra-row rank -----
__global__ __launch_bounds__(256) void count_kernel(
    const int* __restrict__ dst, int* __restrict__ cnt,
    int* __restrict__ rank, int E) {
  int e = blockIdx.x * 256 + threadIdx.x;
  if (e >= E) return;
  rank[e] = atomicAdd(&cnt[dst[e]], 1);
}

// --- scan stage A: per-128-chunk sums --------------------------------------
__global__ __launch_bounds__(128) void scan_block_sum(
    const int* __restrict__ cnt, int* __restrict__ bsum, int N) {
  __shared__ int sd[128];
  int t = threadIdx.x;
  int i = blockIdx.x * 128 + t;
  sd[t] = (i < N) ? cnt[i] : 0;
  __syncthreads();
  for (int off = 64; off > 0; off >>= 1) {
    if (t < off) sd[t] += sd[t + off];
    __syncthreads();
  }
  if (t == 0) bsum[blockIdx.x] = sd[0];
}

// --- scan stage B: exclusive scan of chunk sums (nch <= 1024) --------------
__global__ __launch_bounds__(256) void scan_partials(
    const int* __restrict__ bsum, int* __restrict__ boff, int nch) {
  __shared__ int sd[256];
  int t = threadIdx.x;
  int base = t * 4;
  int v0 = (base + 0 < nch) ? bsum[base + 0] : 0;
  int v1 = (base + 1 < nch) ? bsum[base + 1] : 0;
  int v2 = (base + 2 < nch) ? bsum[base + 2] : 0;
  int v3 = (base + 3 < nch) ? bsum[base + 3] : 0;
  sd[t] = v0 + v1 + v2 + v3;
  __syncthreads();
  for (int off = 1; off < 256; off <<= 1) {
    int x = sd[t];
    int y = (t >= off) ? sd[t - off] : 0;
    __syncthreads();
    sd[t] = x + y;
    __syncthreads();
  }
  int run = (t == 0) ? 0 : sd[t - 1];
  if (base + 0 < nch) boff[base + 0] = run; run += v0;
  if (base + 1 < nch) boff[base + 1] = run; run += v1;
  if (base + 2 < nch) boff[base + 2] = run; run += v2;
  if (base + 3 < nch) boff[base + 3] = run;
}

// --- scan stage C: per-element exclusive offsets -> rowstart ---------------
__global__ __launch_bounds__(128) void scan_final(
    const int* __restrict__ cnt, const int* __restrict__ boff,
    int* __restrict__ rs, int N) {
  __shared__ int sd[128];
  int t = threadIdx.x, b = blockIdx.x;
  int i = b * 128 + t;
  int v = (i < N) ? cnt[i] : 0;
  sd[t] = v;
  __syncthreads();
  for (int off = 1; off < 128; off <<= 1) {
    int x = sd[t];
    int y = (t >= off) ? sd[t - off] : 0;
    __syncthreads();
    sd[t] = x + y;
    __syncthreads();
  }
  if (i < N) rs[i] = boff[b] + ((t == 0) ? 0 : sd[t - 1]);
}

// --- CSR fill, NO atomics: pos = rowstart[dst] + rank ----------------------
__global__ __launch_bounds__(256) void fill_kernel(
    const int* __restrict__ src, const int* __restrict__ dst,
    const float* __restrict__ ea, const int* __restrict__ rs,
    const int* __restrict__ rank, uint2* __restrict__ cidx2, int E) {
  int e = blockIdx.x * 256 + threadIdx.x;
  if (e >= E) return;
  int d = dst[e];
  float2 v = *reinterpret_cast<const float2*>(&ea[2 * (size_t)e]);
  int pos = rs[d] + rank[e];
  cidx2[pos] = make_uint2((unsigned)src[e], pack_f16x2(v.x, v.y));
}

// --- layer-0 x-space aggregation + edge-attr sum (one thread per node) -----
__global__ __launch_bounds__(256) void aggx_kernel(
    const float* __restrict__ x, const int* __restrict__ rs,
    const int* __restrict__ cnt, const uint2* __restrict__ cidx2,
    float* __restrict__ aggx, float* __restrict__ eagg, int N) {
  int i = blockIdx.x * 256 + threadIdx.x;
  if (i >= N) return;
  float4 a = *reinterpret_cast<const float4*>(&x[(size_t)i * 4]);
  float4 b = make_float4(0.f, 0.f, 0.f, 0.f);
  float e0 = 0.f, e1 = 0.f, f0 = 0.f, f1 = 0.f;
  int p = rs[i], e = p + cnt[i];
  for (; p + 1 < e; p += 2) {
    uint2 c0 = cidx2[p], c1 = cidx2[p + 1];
    float4 v0 = *reinterpret_cast<const float4*>(&x[(size_t)c0.x * 4]);
    float4 v1 = *reinterpret_cast<const float4*>(&x[(size_t)c1.x * 4]);
    float2 u0 = unpack_f16x2(c0.y);
    float2 u1 = unpack_f16x2(c1.y);
    a.x += v0.x; a.y += v0.y; a.z += v0.z; a.w += v0.w;
    b.x += v1.x; b.y += v1.y; b.z += v1.z; b.w += v1.w;
    e0 += u0.x; e1 += u0.y;
    f0 += u1.x; f1 += u1.y;
  }
  if (p < e) {
    uint2 c0 = cidx2[p];
    float4 v0 = *reinterpret_cast<const float4*>(&x[(size_t)c0.x * 4]);
    float2 u0 = unpack_f16x2(c0.y);
    a.x += v0.x; a.y += v0.y; a.z += v0.z; a.w += v0.w;
    e0 += u0.x; e1 += u0.y;
  }
  a.x += b.x; a.y += b.y; a.z += b.z; a.w += b.w;
  *reinterpret_cast<float4*>(&aggx[(size_t)i * 4]) = a;
  eagg[2 * (size_t)i + 0] = e0 + f0;
  eagg[2 * (size_t)i + 1] = e1 + f1;
}

// --- pack GEMM weights into MFMA-frag-contiguous f16 layout ----------------
__global__ __launch_bounds__(256) void pack_weights_kernel(
    const float* __restrict__ Wn0, const float* __restrict__ Ws0,
    const float* __restrict__ Wn1, const float* __restrict__ Ws1,
    const float* __restrict__ Wn2, const float* __restrict__ Ws2,
    const float* __restrict__ Wj, _Float16* __restrict__ outp) {
  int i = blockIdx.x * 256 + threadIdx.x;
  if (i >= 147456) return;
  int j = i & 7, lane = (i >> 3) & 63;
  float v;
  if (i < 98304) {
    int l = i >> 15;
    int r = i & 32767;
    int nt = (r >> 9) & 7, kt = r >> 12;
    int k = kt * 32 + (lane >> 4) * 8 + j;
    int n = nt * 16 + (lane & 15);
    const float* Wn = (l == 0) ? Wn0 : (l == 1) ? Wn1 : Wn2;
    const float* Ws = (l == 0) ? Ws0 : (l == 1) ? Ws1 : Ws2;
    v = (k < 128) ? Wn[(size_t)k * HDIM + n] : Ws[(size_t)(k - 128) * HDIM + n];
  } else {
    int r = i - 98304;
    int nt = (r >> 9) & 7, kt = r >> 12;  // kt 0..11
    int k = kt * 32 + (lane >> 4) * 8 + j;
    int n = nt * 16 + (lane & 15);
    v = Wj[(size_t)k * HDIM + n];
  }
  outp[i] = (_Float16)v;
}

// --- fused SAGE layer on MFMA (gather fused for L != 0) --------------------
// Block: 64 rows, 4 waves; wave w owns rows w*16..w*16+15, all 128 cols.
// L0:  A = [ (aggx*inv)@Wi + bi | x@Wi + bi ]   (f32 sources).
// else: A = [ mean(h[nbrs]+self) | h_prev ]     (gathered in staging).
// outh(f16, pre-BN) = relu(A@B + (eagg*inv) x Wn[128:130]); BN partials f32.
template <bool L0>
__global__ __launch_bounds__(256) void sage_mfma_kernel(
    const float* __restrict__ A0f, const float* __restrict__ A1f,
    const _Float16* __restrict__ Hprev, const int* __restrict__ rs,
    const uint2* __restrict__ cidx2,
    const float* __restrict__ Wi, const float* __restrict__ bi,
    const float* __restrict__ eagg, const int* __restrict__ cnt,
    const _Float16* __restrict__ Bp, const float* __restrict__ Wn,
    _Float16* __restrict__ outh, float* __restrict__ bnstat, int N) {
  __shared__ _Float16 sA[64 * 256];  // 32 KB, XOR-swizzled rows
  __shared__ float sE[128];          // e0,e1 per row (pre-scaled)
  __shared__ float sBNs[4][128];
  __shared__ float sBNq[4][128];
  const int t = threadIdx.x;
  const int base = blockIdx.x * 64;

  if (t < 64) {
    int grow = base + t;
    float e0 = 0.f, e1 = 0.f;
    if (grow < N) {
      float inv = 1.0f / ((float)cnt[grow] + 1.0f);
      e0 = eagg[2 * (size_t)grow] * inv;
      e1 = eagg[2 * (size_t)grow + 1] * inv;
    }
    sE[2 * t] = e0;
    sE[2 * t + 1] = e1;
  }

  if (L0) {
    // stage A tile from x-space projections (as round 4)
#pragma unroll
    for (int it = 0; it < 8; ++it) {
      int c = t + it * 256;
      int row = c >> 5, k8 = c & 31;
      int grow = base + row;
      f16x8 hv = {};
      if (grow < N) {
        float inv = 1.0f / ((float)cnt[grow] + 1.0f);
        float scale = (k8 < 16) ? inv : 1.0f;
        const float* rp = (k8 < 16) ? &A0f[(size_t)grow * 4] : &A1f[(size_t)grow * 4];
        float4 r = *reinterpret_cast<const float4*>(rp);
        int col0 = (k8 & 15) * 8;
#pragma unroll
        for (int jj = 0; jj < 8; ++jj) {
          int col = col0 + jj;
          hv[jj] = (_Float16)(bi[col] + scale * (r.x * Wi[col] + r.y * Wi[HDIM + col] +
                                                 r.z * Wi[2 * HDIM + col] + r.w * Wi[3 * HDIM + col]));
        }
      }
      int byte = (row * 512 + k8 * 16) ^ ((row & 7) << 4);
      *reinterpret_cast<f16x8*>(reinterpret_cast<char*>(sA) + byte) = hv;
    }
  } else {
    // fused gather: thread t -> row t>>2, column quarter q = t&3 (32 cols)
    const int row = t >> 2, q = t & 3;
    const int grow = base + row;
    float acc[32];
#pragma unroll
    for (int c = 0; c < 32; ++c) acc[c] = 0.f;
    f16x8 selfv[4] = {};
    if (grow < N) {
      const f16x8* selfp = reinterpret_cast<const f16x8*>(Hprev + (size_t)grow * HDIM) + q * 4;
#pragma unroll
      for (int j = 0; j < 4; ++j) {
        selfv[j] = selfp[j];
#pragma unroll
        for (int jj = 0; jj < 8; ++jj) acc[j * 8 + jj] = (float)selfv[j][jj];
      }
      int p = rs[grow];
      int e = p + cnt[grow];
      for (; p + 1 < e; p += 2) {
        uint2 q0 = cidx2[p], q1 = cidx2[p + 1];
        const f16x8* n0 = reinterpret_cast<const f16x8*>(Hprev + (size_t)q0.x * HDIM) + q * 4;
        const f16x8* n1 = reinterpret_cast<const f16x8*>(Hprev + (size_t)q1.x * HDIM) + q * 4;
        f16x8 c0[4], c1[4];
#pragma unroll
        for (int j = 0; j < 4; ++j) c0[j] = n0[j];
#pragma unroll
        for (int j = 0; j < 4; ++j) c1[j] = n1[j];
#pragma unroll
        for (int j = 0; j < 4; ++j)
#pragma unroll
          for (int jj = 0; jj < 8; ++jj)
            acc[j * 8 + jj] += (float)c0[j][jj] + (float)c1[j][jj];
      }
      if (p < e) {
        uint2 q0 = cidx2[p];
        const f16x8* n0 = reinterpret_cast<const f16x8*>(Hprev + (size_t)q0.x * HDIM) + q * 4;
#pragma unroll
        for (int j = 0; j < 4; ++j) {
          f16x8 c0 = n0[j];
#pragma unroll
          for (int jj = 0; jj < 8; ++jj) acc[j * 8 + jj] += (float)c0[jj];
        }
      }
      float inv = 1.0f / ((float)cnt[grow] + 1.0f);
#pragma unroll
      for (int c = 0; c < 32; ++c) acc[c] *= inv;
    }
    const int swz = (row & 7) << 4;
#pragma unroll
    for (int j = 0; j < 4; ++j) {
      f16x8 av;
#pragma unroll
      for (int jj = 0; jj < 8; ++jj) av[jj] = (_Float16)acc[j * 8 + jj];
      int k8a = q * 4 + j;
      *reinterpret_cast<f16x8*>(reinterpret_cast<char*>(sA) +
                                ((row * 512 + k8a * 16) ^ swz)) = av;
      int k8h = 16 + q * 4 + j;
      *reinterpret_cast<f16x8*>(reinterpret_cast<char*>(sA) +
                                ((row * 512 + k8h * 16) ^ swz)) = selfv[j];
    }
  }
  __syncthreads();

  const int lane = t & 63;
  const int w = t >> 6;
  const int col16 = lane & 15;
  const int kgrp = lane >> 4;
  f32x4 acc[8];
#pragma unroll
  for (int nt = 0; nt < 8; ++nt) acc[nt] = (f32x4){0.f, 0.f, 0.f, 0.f};

  const int arow = w * 16 + col16;
  const int aswz = (arow & 7) << 4;
#pragma unroll
  for (int kt = 0; kt < 8; ++kt) {
    int abyte = (arow * 512 + kt * 64 + kgrp * 16) ^ aswz;
    f16x8 a = *reinterpret_cast<const f16x8*>(reinterpret_cast<const char*>(sA) + abyte);
    const f16x8* bp = reinterpret_cast<const f16x8*>(Bp) + (size_t)kt * 512 + lane;
#pragma unroll
    for (int nt = 0; nt < 8; ++nt) {
      f16x8 b = bp[nt * 64];
      acc[nt] = __builtin_amdgcn_mfma_f32_16x16x32_f16(a, b, acc[nt], 0, 0, 0);
    }
  }

  // epilogue: edge-attr rank-2 update + relu + f16 store + BN partials
#pragma unroll
  for (int nt = 0; nt < 8; ++nt) {
    int col = nt * 16 + col16;
    float we0 = Wn[(size_t)128 * HDIM + col];
    float we1 = Wn[(size_t)129 * HDIM + col];
    float s = 0.f, q = 0.f;
#pragma unroll
    for (int i = 0; i < 4; ++i) {
      int lr = w * 16 + kgrp * 4 + i;
      int row = base + lr;
      if (row < N) {
        float v = acc[nt][i] + sE[2 * lr] * we0 + sE[2 * lr + 1] * we1;
        v = fmaxf(v, 0.f);
        outh[(size_t)row * HDIM + col] = (_Float16)v;
        s += v;
        q += v * v;
      }
    }
    s += __shfl_xor(s, 16, 64);
    s += __shfl_xor(s, 32, 64);
    q += __shfl_xor(q, 16, 64);
    q += __shfl_xor(q, 32, 64);
    if (lane < 16) {
      sBNs[w][col] = s;
      sBNq[w][col] = q;
    }
  }
  __syncthreads();
  if (t < 128) {
    float s = sBNs[0][t] + sBNs[1][t] + sBNs[2][t] + sBNs[3][t];
    float q = sBNq[0][t] + sBNq[1][t] + sBNq[2][t] + sBNq[3][t];
    atomicAdd(&bnstat[t], s);
    atomicAdd(&bnstat[HDIM + t], q);
  }
}

// --- BN finalize (in-block) + apply + L2 normalize: f16 in, f16 out --------
__global__ __launch_bounds__(256) void bn_l2_kernel(
    const _Float16* __restrict__ outh, const float* __restrict__ stat,
    const float* __restrict__ gamma, const float* __restrict__ beta,
    float invN, _Float16* __restrict__ h, int N) {
  __shared__ float sAB[256];
  int t = threadIdx.x;
  if (t < 128) {
    float mean = stat[t] * invN;
    float var = stat[128 + t] * invN - mean * mean;
    float A = gamma[t] / sqrtf(var + 1e-5f);
    sAB[t] = A;
    sAB[128 + t] = beta[t] - mean * A;
  }
  __syncthreads();
  int i = blockIdx.x * 4 + (t >> 6);
  if (i >= N) return;
  int lane = t & 63;
  unsigned u = (reinterpret_cast<const unsigned*>(outh + (size_t)i * HDIM))[lane];
  float2 v = unpack_f16x2(u);
  float A0 = sAB[lane * 2 + 0], A1 = sAB[lane * 2 + 1];
  float B0 = sAB[128 + lane * 2 + 0], B1 = sAB[128 + lane * 2 + 1];
  float y0 = v.x * A0 + B0;
  float y1 = v.y * A1 + B1;
  float s = y0 * y0 + y1 * y1;
#pragma unroll
  for (int m = 32; m > 0; m >>= 1) s += __shfl_xor(s, m, 64);
  float inv = 1.0f / fmaxf(sqrtf(s), 1e-12f);
  (reinterpret_cast<unsigned*>(h + (size_t)i * HDIM))[lane] =
      pack_f16x2(y0 * inv, y1 * inv);
}

// --- jump GEMM (MFMA, K=384, f16 h inputs) + scorer MLP --------------------
__global__ __launch_bounds__(256) void jump_mfma_kernel(
    const _Float16* __restrict__ h1, const _Float16* __restrict__ h2,
    const _Float16* __restrict__ h3, const _Float16* __restrict__ Bp,
    const float* __restrict__ bj, const float* __restrict__ W1p,
    const float* __restrict__ b1p, const float* __restrict__ W2p,
    const float* __restrict__ b2p, float* __restrict__ outp, int N) {
  __shared__ _Float16 sA[64 * 384];  // 48 KB; reused: sG[64*128] f32 + sS[64*64] f32
  const int t = threadIdx.x;
  const int base = blockIdx.x * 64;

  const _Float16* hs[3] = {h1, h2, h3};
#pragma unroll
  for (int it = 0; it < 12; ++it) {
    int c = t + it * 256;
    int row = c / 48, k8 = c % 48;
    int grow = base + row;
    f16x8 hv = {};
    if (grow < N)
      hv = (reinterpret_cast<const f16x8*>(hs[k8 >> 4] + (size_t)grow * HDIM))[k8 & 15];
    int byte = (row * 768 + k8 * 16) ^ ((row & 7) << 4);
    *reinterpret_cast<f16x8*>(reinterpret_cast<char*>(sA) + byte) = hv;
  }
  __syncthreads();

  const int lane = t & 63;
  const int w = t >> 6;
  const int col16 = lane & 15;
  const int kgrp = lane >> 4;
  f32x4 acc[8];
#pragma unroll
  for (int nt = 0; nt < 8; ++nt) acc[nt] = (f32x4){0.f, 0.f, 0.f, 0.f};

  const int arow = w * 16 + col16;
  const int aswz = (arow & 7) << 4;
#pragma unroll
  for (int kt = 0; kt < 12; ++kt) {
    int abyte = (arow * 768 + kt * 64 + kgrp * 16) ^ aswz;
    f16x8 a = *reinterpret_cast<const f16x8*>(reinterpret_cast<const char*>(sA) + abyte);
    const f16x8* bp = reinterpret_cast<const f16x8*>(Bp) + (size_t)kt * 512 + lane;
#pragma unroll
    for (int nt = 0; nt < 8; ++nt) {
      f16x8 b = bp[nt * 64];
      acc[nt] = __builtin_amdgcn_mfma_f32_16x16x32_f16(a, b, acc[nt], 0, 0, 0);
    }
  }
  __syncthreads();  // all waves done reading sA -> safe to alias

  float* sG = reinterpret_cast<float*>(sA);
  float* sS = sG + 64 * 128;
#pragma unroll
  for (int nt = 0; nt < 8; ++nt) {
    int col = nt * 16 + col16;
    float bb = bj[col];
#pragma unroll
    for (int i = 0; i < 4; ++i) {
      int lr = w * 16 + kgrp * 4 + i;
      sG[lr * 128 + col] = fmaxf(acc[nt][i] + bb, 0.f);
    }
  }
  __syncthreads();

  const int m = t & 63, grp = t >> 6;
  float a2[16];
#pragma unroll
  for (int i = 0; i < 16; ++i) a2[i] = b1p[m];
#pragma unroll 4
  for (int k = 0; k < 128; ++k) {
    float wv = W1p[(size_t)k * 64 + m];
#pragma unroll
    for (int i = 0; i < 16; ++i) a2[i] += sG[(grp * 16 + i) * 128 + k] * wv;
  }
#pragma unroll
  for (int i = 0; i < 16; ++i) sS[(grp * 16 + i) * 64 + m] = fmaxf(a2[i], 0.f);
  __syncthreads();

  if (t < 64) {
    int row = base + t;
    if (row < N) {
      float s = b2p[0];
#pragma unroll 8
      for (int mm = 0; mm < 64; ++mm) s += sS[t * 64 + mm] * W2p[mm];
      outp[row] = s;
    }
  }
}

// ---------------------------------------------------------------------------
extern "C" void kernel_launch(void* const* d_in, const int* in_sizes, int n_in,
                              void* d_out, int out_size, void* d_ws, size_t ws_size,
                              hipStream_t stream) {
  const float* x      = (const float*)d_in[0];
  const int*   ei     = (const int*)d_in[1];
  const float* eattr  = (const float*)d_in[2];
  const float* W_in   = (const float*)d_in[3];
  const float* b_in   = (const float*)d_in[4];
  const float* W_jump = (const float*)d_in[5];
  const float* b_jump = (const float*)d_in[6];
  const float* W1     = (const float*)d_in[7];
  const float* b1     = (const float*)d_in[8];
  const float* W2     = (const float*)d_in[9];
  const float* b2     = (const float*)d_in[10];
  const float* Wn[3] = {(const float*)d_in[11], (const float*)d_in[15], (const float*)d_in[19]};
  const float* Ws[3] = {(const float*)d_in[12], (const float*)d_in[16], (const float*)d_in[20]};
  const float* gm[3] = {(const float*)d_in[13], (const float*)d_in[17], (const float*)d_in[21]};
  const float* bt[3] = {(const float*)d_in[14], (const float*)d_in[18], (const float*)d_in[22]};

  const int N = in_sizes[0] / 4;
  const int E = in_sizes[2] / 2;
  const int* srcp = ei;
  const int* dstp = ei + (size_t)E;
  const int nch = (N + 127) / 128;
  const size_t nh = (size_t)N * HDIM;

  // --- workspace carve-up (256B aligned blocks) ---
  char* wsb = (char*)d_ws;
  size_t off = 0;
  auto carve = [&](size_t bytes) -> void* {
    void* p = wsb + off;
    off = (off + bytes + 255) & ~(size_t)255;
    return p;
  };
  _Float16* h1   = (_Float16*)carve(nh * 2);
  _Float16* h2   = (_Float16*)carve(nh * 2);
  _Float16* h3   = (_Float16*)carve(nh * 2);
  _Float16* outh = (_Float16*)carve(nh * 2);
  float*    aggx = (float*)carve((size_t)N * 4 * 4);
  float*    eagg = (float*)carve((size_t)N * 2 * 4);
  int*      cnt  = (int*)carve((size_t)N * 4);
  int*      rowstart = (int*)carve((size_t)N * 4);
  int*      rank     = (int*)carve((size_t)E * 4);
  uint2*    cidx2    = (uint2*)carve((size_t)E * 8);
  int*      bsum = (int*)carve(4096);
  int*      boff = (int*)carve(4096);
  float*    bnstat = (float*)carve(1024);
  _Float16* wpack  = (_Float16*)carve(147456 * 2);

  // --- CSR build + weight pack (layer-invariant) ---
  hipMemsetAsync(cnt, 0, (size_t)N * sizeof(int), stream);
  count_kernel<<<(E + 255) / 256, 256, 0, stream>>>(dstp, cnt, rank, E);
  pack_weights_kernel<<<(147456 + 255) / 256, 256, 0, stream>>>(
      Wn[0], Ws[0], Wn[1], Ws[1], Wn[2], Ws[2], W_jump, wpack);
  scan_block_sum<<<nch, 128, 0, stream>>>(cnt, bsum, N);
  scan_partials<<<1, 256, 0, stream>>>(bsum, boff, nch);
  scan_final<<<nch, 128, 0, stream>>>(cnt, boff, rowstart, N);
  fill_kernel<<<(E + 255) / 256, 256, 0, stream>>>(srcp, dstp, eattr, rowstart, rank, cidx2, E);

  const int gemm_grid = (N + 63) / 64;
  const float invN = 1.0f / (float)N;

  // --- layer 0 (aggregation folded into x-space; eagg computed here) ---
  aggx_kernel<<<(N + 255) / 256, 256, 0, stream>>>(x, rowstart, cnt, cidx2, aggx, eagg, N);
  hipMemsetAsync(bnstat, 0, 256 * sizeof(float), stream);
  sage_mfma_kernel<true><<<gemm_grid, 256, 0, stream>>>(
      aggx, x, nullptr, rowstart, cidx2, W_in, b_in, eagg, cnt, wpack, Wn[0],
      outh, bnstat, N);
  bn_l2_kernel<<<(N + 3) / 4, 256, 0, stream>>>(outh, bnstat, gm[0], bt[0], invN, h1, N);

  // --- layers 1,2 (gather fused into sage staging) ---
  _Float16* hbuf[3] = {h1, h2, h3};
  for (int l = 1; l < 3; ++l) {
    hipMemsetAsync(bnstat, 0, 256 * sizeof(float), stream);
    sage_mfma_kernel<false><<<gemm_grid, 256, 0, stream>>>(
        nullptr, nullptr, hbuf[l - 1], rowstart, cidx2, nullptr, nullptr, eagg, cnt,
        wpack + (size_t)l * 32768, Wn[l], outh, bnstat, N);
    bn_l2_kernel<<<(N + 3) / 4, 256, 0, stream>>>(outh, bnstat, gm[l], bt[l], invN, hbuf[l], N);
  }

  jump_mfma_kernel<<<gemm_grid, 256, 0, stream>>>(h1, h2, h3, wpack + 98304, b_jump,
                                                  W1, b1, W2, b2, (float*)d_out, N);
}